// Round 3
// baseline (546.789 us; speedup 1.0000x reference)
//
#include <hip/hip_runtime.h>
#include <cstdint>

typedef short bf16x8 __attribute__((ext_vector_type(8)));
typedef float f32x4 __attribute__((ext_vector_type(4)));
#define MFMA16(a, b, c) __builtin_amdgcn_mfma_f32_16x16x32_bf16((a), (b), (c), 0, 0, 0)

static __device__ __forceinline__ float sigmoidf_(float x) { return 1.f / (1.f + __expf(-x)); }
static __device__ __forceinline__ unsigned short f2bf(float f) {
  union { float f; unsigned u; } v; v.f = f;
  unsigned r = v.u + 0x7FFF + ((v.u >> 16) & 1);
  return (unsigned short)(r >> 16);
}

// ---------------- K0: weight prep (frag layouts for MFMA convs), W2, zero cnn_sum -------
__global__ __launch_bounds__(256) void k_prep(
    const float* __restrict__ c1_w, const float* __restrict__ c2_w,
    const float* __restrict__ fc_w, const float* __restrict__ opw,
    unsigned short* __restrict__ Wf1, unsigned short* __restrict__ Wf2,
    float* __restrict__ W2, float* __restrict__ cnn_sum)
{
  int i = blockIdx.x * 256 + threadIdx.x;
  if (i < 36864) {           // Wf2[t][cf 0..7][lane][j] = c2_w[co][ci][dy][dx]
    int j = i & 7, l = (i >> 3) & 63, m = (i >> 9) & 7, t = i >> 12;
    int co = m * 16 + (l & 15), ci = ((l >> 4) << 3) + j;
    Wf2[i] = f2bf(c2_w[(size_t)(co * 32 + ci) * 9 + t]);
  } else if (i < 46080) {    // Wf1[t][cf 0..1][lane][j]
    int ii = i - 36864;
    int j = ii & 7, l = (ii >> 3) & 63, m = (ii >> 9) & 1, t = ii >> 10;
    int co = m * 16 + (l & 15), ci = ((l >> 4) << 3) + j;
    Wf1[ii] = f2bf(c1_w[(size_t)(co * 32 + ci) * 9 + t]);
  } else if (i < 54272) {    // W2 = fc_w @ out_proj_w (128x64)
    int ii = i - 46080;
    int f = ii >> 6, d2 = ii & 63;
    float a = 0.f;
    #pragma unroll
    for (int dm = 0; dm < 32; dm++) a = fmaf(fc_w[(f << 5) + dm], opw[(dm << 6) + d2], a);
    W2[ii] = a;
  } else if (i < 70656) {
    cnn_sum[i - 54272] = 0.f;
  }
}

// ---------------- K1: 1x1 conv (proj) + BN0 + ReLU -> p_tok (f32), p_bf (bf16) ----------
__global__ __launch_bounds__(256) void k_proj_bn(
    const float* __restrict__ x, const float* __restrict__ w,
    const float* __restrict__ pb,
    const float* __restrict__ g, const float* __restrict__ be,
    const float* __restrict__ mm, const float* __restrict__ vv,
    float* __restrict__ p_tok, unsigned short* __restrict__ p_bf)
{
  __shared__ float wl[6400];        // [c][d] transposed proj_w
  __shared__ float sc[32], sb[32];
  int b = blockIdx.x >> 2, ch = blockIdx.x & 3;
  for (int i = threadIdx.x; i < 6400; i += 256) {
    int c = i >> 5, d = i & 31;
    wl[i] = w[d * 200 + c];
  }
  if (threadIdx.x < 32) {
    int d = threadIdx.x;
    float s = g[d] * rsqrtf(vv[d] + 1e-5f);
    sc[d] = s;
    sb[d] = fmaf(pb[d] - mm[d], s, be[d]);
  }
  __syncthreads();
  int l = (ch << 8) + threadIdx.x;
  const float* xp = x + (size_t)b * 200 * 1024 + l;
  float acc[32];
  #pragma unroll
  for (int d = 0; d < 32; d++) acc[d] = 0.f;
  for (int c = 0; c < 200; c++) {
    float xv = xp[(size_t)c << 10];
    const float* wr = &wl[c << 5];
    #pragma unroll
    for (int d = 0; d < 32; d++) acc[d] = fmaf(xv, wr[d], acc[d]);
  }
  #pragma unroll
  for (int d = 0; d < 32; d++) {
    float val = fmaf(acc[d], sc[d], sb[d]);
    acc[d] = fmaxf(val, 0.f);
  }
  float* pt = p_tok + (((size_t)b << 10) + l) * 32;
  #pragma unroll
  for (int d = 0; d < 32; d += 4)
    *reinterpret_cast<float4*>(pt + d) = make_float4(acc[d], acc[d+1], acc[d+2], acc[d+3]);
  unsigned short* pbf = p_bf + (((size_t)b << 10) + l) * 32;
  #pragma unroll
  for (int k = 0; k < 4; k++) {
    uint4 q;
    q.x = (unsigned)f2bf(acc[8*k+0]) | ((unsigned)f2bf(acc[8*k+1]) << 16);
    q.y = (unsigned)f2bf(acc[8*k+2]) | ((unsigned)f2bf(acc[8*k+3]) << 16);
    q.z = (unsigned)f2bf(acc[8*k+4]) | ((unsigned)f2bf(acc[8*k+5]) << 16);
    q.w = (unsigned)f2bf(acc[8*k+6]) | ((unsigned)f2bf(acc[8*k+7]) << 16);
    *reinterpret_cast<uint4*>(pbf + k * 8) = q;
  }
}

// ---------------- K2: FUSED mamba (in_proj -> dwconv -> x_proj -> softplus -> scan) -----
// grid 256 = (b, d-half); 512 threads; all intermediates in LDS; only p_tok read, ybar out.
__global__ __launch_bounds__(512) void k_mamba(
    const float* __restrict__ p_tok,
    const float* __restrict__ in_w,      // (128,32)
    const float* __restrict__ conv_w,    // (64,4)
    const float* __restrict__ conv_b,    // (64)
    const float* __restrict__ xp_w,      // (34,64)
    const float* __restrict__ dt_w,      // (64,2)
    const float* __restrict__ dt_b,      // (64)
    const float* __restrict__ A_log,     // (64,16)
    const float* __restrict__ Dp,        // (64)
    float* __restrict__ ybar)            // (128,64)
{
  __shared__ __align__(16) char smem[62256];
  float* xm   = (float*)smem;               // [67][68]  rows r = token t+3; rows 0..2 history
  float* dlS  = (float*)(smem + 816);       // [32][68]  alias xm rows 3..34 (delta, d-major)
  float* uS   = (float*)(smem + 18224);     // [64][68]  u, t-major (for x_proj)
  float* uT   = (float*)(smem + 35632);     // [32][68]  own-half u, d-major (for scan)
  float* zsT  = (float*)(smem + 44336);     // [32][68]  own-half silu(z), d-major
  float* bcT  = (float*)(smem + 53040);     // [32][68]  rows 0..15 B[n][t], 16..31 C[n][t]
  float* tokL = (float*)(smem + 53040);     // [67][32]  alias bcT (tokens, phase1 only)
  float* dt01 = (float*)(smem + 61744);     // [64][2]

  int b = blockIdx.x >> 1, hh = blockIdx.x & 1;
  int tid = threadIdx.x;

  // --- persistent per-role registers ---
  int p2d = tid & 63;                       // phase2 (dwconv) channel
  float4 cw4 = *reinterpret_cast<const float4*>(&conv_w[p2d << 2]);
  float cb1 = conv_b[p2d];
  int og = tid & 7;                         // dt01 o-slice
  float xw0[8], xw1[8];
  #pragma unroll
  for (int q = 0; q < 8; q++) {
    xw0[q] = xp_w[(og << 3) + q];
    xw1[q] = xp_w[64 + (og << 3) + q];
  }
  int dd = tid & 7;                         // phase4 d-group
  float dtw0[4], dtw1[4], dtb4[4];
  #pragma unroll
  for (int q = 0; q < 4; q++) {
    int dg = (hh << 5) + (dd << 2) + q;
    dtw0[q] = dt_w[2 * dg]; dtw1[q] = dt_w[2 * dg + 1]; dtb4[q] = dt_b[dg];
  }
  int sdl = tid >> 4, sn = tid & 15;        // scan (d_local, n)
  int sdg = (hh << 5) + sdl;
  float Areg = -__expf(A_log[(sdg << 4) + sn]);
  float hst = 0.f, acc_n = 0.f, acc_u = 0.f;
  int p1o = tid & 127, p1tg = tid >> 7;     // phase1 (o, t-group)
  int p3j = tid & 31, p3tg = tid >> 5;      // phase3 (j', t-group)

  const float* ptb = p_tok + ((size_t)b << 15);

  for (int ch = 0; ch < 16; ch++) {
    __syncthreads();                        // prev chunk's scan done
    // history rows + token staging (tokL aliases bcT — prev scan complete)
    if (tid < 192) {
      int r = tid >> 6, d = tid & 63;
      xm[r * 68 + d] = (ch == 0) ? 0.f : xm[(64 + r) * 68 + d];
    }
    for (int i = tid; i < 2144; i += 512) {
      int r = i >> 5, c = i & 31;
      int tg_ = (ch << 6) + r - 3;
      tokL[i] = (tg_ >= 0) ? ptb[(tg_ << 5) + c] : 0.f;
    }
    __syncthreads();                        // A
    // ---- phase1: xz = tok @ in_w^T (weights in regs, tok broadcast b128) ----
    {
      float4 w4[8];
      const float* wr = &in_w[p1o << 5];
      #pragma unroll
      for (int c4 = 0; c4 < 8; c4++) w4[c4] = *reinterpret_cast<const float4*>(&wr[c4 << 2]);
      float accv[16];
      #pragma unroll
      for (int tt = 0; tt < 16; tt++) {
        const float* trow = &tokL[((p1tg << 4) + tt + 3) << 5];
        float a = 0.f;
        #pragma unroll
        for (int c4 = 0; c4 < 8; c4++) {
          float4 tv = *reinterpret_cast<const float4*>(&trow[c4 << 2]);
          a = fmaf(tv.x, w4[c4].x, a); a = fmaf(tv.y, w4[c4].y, a);
          a = fmaf(tv.z, w4[c4].z, a); a = fmaf(tv.w, w4[c4].w, a);
        }
        accv[tt] = a;
      }
      if (p1o < 64) {
        #pragma unroll
        for (int tt = 0; tt < 16; tt++)
          xm[((p1tg << 4) + tt + 3) * 68 + p1o] = accv[tt];
      } else {
        int dz = p1o - 64;
        if ((dz >> 5) == hh) {
          int dzl = dz & 31;
          #pragma unroll
          for (int tt = 0; tt < 16; tt++) {
            float a = accv[tt];
            zsT[dzl * 68 + (p1tg << 4) + tt] = a * sigmoidf_(a);
          }
        }
      }
    }
    __syncthreads();                        // B: xm, zsT ready
    // ---- phase2: causal dwconv(4) + silu -> uS (t-major), uT (own-half d-major) ----
    {
      int t0 = (tid >> 6) << 3;
      float x0 = xm[(t0 + 0) * 68 + p2d], x1 = xm[(t0 + 1) * 68 + p2d], x2 = xm[(t0 + 2) * 68 + p2d];
      bool own = (p2d >> 5) == hh;
      int dol = p2d & 31;
      #pragma unroll
      for (int s = 0; s < 8; s++) {
        int t = t0 + s;
        float x3 = xm[(t + 3) * 68 + p2d];
        float a = cb1;
        a = fmaf(cw4.x, x0, a); a = fmaf(cw4.y, x1, a);
        a = fmaf(cw4.z, x2, a); a = fmaf(cw4.w, x3, a);
        float uu = a * sigmoidf_(a);
        uS[t * 68 + p2d] = uu;
        if (own) uT[dol * 68 + t] = uu;
        x0 = x1; x1 = x2; x2 = x3;
      }
    }
    __syncthreads();                        // C: uS, uT ready
    // ---- phase3a: B/C = u @ xp_w[2:34]^T (weights in regs) -> bcT ----
    {
      float4 xw4[16];
      const float* xwr = &xp_w[(2 + p3j) << 6];
      #pragma unroll
      for (int o4 = 0; o4 < 16; o4++) xw4[o4] = *reinterpret_cast<const float4*>(&xwr[o4 << 2]);
      #pragma unroll
      for (int s = 0; s < 4; s++) {
        int t = (p3tg << 2) + s;
        const float* ur = &uS[t * 68];
        float a = 0.f;
        #pragma unroll
        for (int o4 = 0; o4 < 16; o4++) {
          float4 uv = *reinterpret_cast<const float4*>(&ur[o4 << 2]);
          a = fmaf(uv.x, xw4[o4].x, a); a = fmaf(uv.y, xw4[o4].y, a);
          a = fmaf(uv.z, xw4[o4].z, a); a = fmaf(uv.w, xw4[o4].w, a);
        }
        bcT[p3j * 68 + t] = a;
      }
    }
    // ---- dt01: xdbl[:, 0:2] via 8-lane partial + shuffle reduce ----
    {
      int t = tid >> 3;
      const float* ur = &uS[t * 68 + (og << 3)];
      float4 ua = *reinterpret_cast<const float4*>(&ur[0]);
      float4 ub = *reinterpret_cast<const float4*>(&ur[4]);
      float a0 = 0.f, a1 = 0.f;
      a0 = fmaf(ua.x, xw0[0], a0); a0 = fmaf(ua.y, xw0[1], a0);
      a0 = fmaf(ua.z, xw0[2], a0); a0 = fmaf(ua.w, xw0[3], a0);
      a0 = fmaf(ub.x, xw0[4], a0); a0 = fmaf(ub.y, xw0[5], a0);
      a0 = fmaf(ub.z, xw0[6], a0); a0 = fmaf(ub.w, xw0[7], a0);
      a1 = fmaf(ua.x, xw1[0], a1); a1 = fmaf(ua.y, xw1[1], a1);
      a1 = fmaf(ua.z, xw1[2], a1); a1 = fmaf(ua.w, xw1[3], a1);
      a1 = fmaf(ub.x, xw1[4], a1); a1 = fmaf(ub.y, xw1[5], a1);
      a1 = fmaf(ub.z, xw1[6], a1); a1 = fmaf(ub.w, xw1[7], a1);
      a0 += __shfl_xor(a0, 1); a0 += __shfl_xor(a0, 2); a0 += __shfl_xor(a0, 4);
      a1 += __shfl_xor(a1, 1); a1 += __shfl_xor(a1, 2); a1 += __shfl_xor(a1, 4);
      if (og == 0) { dt01[t * 2] = a0; dt01[t * 2 + 1] = a1; }
    }
    __syncthreads();                        // D: bcT, dt01 ready
    // ---- phase4: delta = softplus(dt @ dt_w^T + dt_b) -> dlS (d-major, own half) ----
    {
      int t = tid >> 3;
      float d0 = dt01[t * 2], d1 = dt01[t * 2 + 1];
      #pragma unroll
      for (int q = 0; q < 4; q++) {
        float pre = fmaf(d0, dtw0[q], fmaf(d1, dtw1[q], dtb4[q]));
        float dl_ = (pre > 20.f) ? pre : log1pf(__expf(pre));
        dlS[((dd << 2) + q) * 68 + t] = dl_;
      }
    }
    __syncthreads();                        // E: dlS ready
    // ---- scan: 64 sequential steps, all float4 LDS reads ----
    {
      const float* dr = &dlS[sdl * 68];
      const float* ur = &uT[sdl * 68];
      const float* zr = &zsT[sdl * 68];
      const float* Br = &bcT[sn * 68];
      const float* Cr = &bcT[(16 + sn) * 68];
      for (int t = 0; t < 64; t += 4) {
        float4 dv = *reinterpret_cast<const float4*>(&dr[t]);
        float4 uv = *reinterpret_cast<const float4*>(&ur[t]);
        float4 zv = *reinterpret_cast<const float4*>(&zr[t]);
        float4 Bv = *reinterpret_cast<const float4*>(&Br[t]);
        float4 Cv = *reinterpret_cast<const float4*>(&Cr[t]);
        float e0 = __expf(dv.x * Areg), e1 = __expf(dv.y * Areg);
        float e2 = __expf(dv.z * Areg), e3 = __expf(dv.w * Areg);
        float k0 = dv.x * uv.x * Bv.x, k1 = dv.y * uv.y * Bv.y;
        float k2 = dv.z * uv.z * Bv.z, k3 = dv.w * uv.w * Bv.w;
        float c0 = Cv.x * zv.x, c1 = Cv.y * zv.y;
        float c2 = Cv.z * zv.z, c3 = Cv.w * zv.w;
        hst = fmaf(e0, hst, k0); acc_n = fmaf(hst, c0, acc_n);
        hst = fmaf(e1, hst, k1); acc_n = fmaf(hst, c1, acc_n);
        hst = fmaf(e2, hst, k2); acc_n = fmaf(hst, c2, acc_n);
        hst = fmaf(e3, hst, k3); acc_n = fmaf(hst, c3, acc_n);
        acc_u = fmaf(uv.x, zv.x, acc_u); acc_u = fmaf(uv.y, zv.y, acc_u);
        acc_u = fmaf(uv.z, zv.z, acc_u); acc_u = fmaf(uv.w, zv.w, acc_u);
      }
    }
  }
  // reduce acc_n over n lanes
  float y = acc_n;
  y += __shfl_xor(y, 1); y += __shfl_xor(y, 2);
  y += __shfl_xor(y, 4); y += __shfl_xor(y, 8);
  if (sn == 0)
    ybar[(b << 6) + sdg] = (y + Dp[sdg] * acc_u) * (1.f / 1024.f);
}

// ---------------- K3a: conv1 3x3 VALID (32->32) + BN1 + ReLU, MFMA, -> c1_bf -------------
__global__ __launch_bounds__(256) void k_conv1m(
    const unsigned short* __restrict__ p_bf, const unsigned short* __restrict__ Wf1,
    const float* __restrict__ cbias,
    const float* __restrict__ g, const float* __restrict__ be,
    const float* __restrict__ mm, const float* __restrict__ vv,
    unsigned short* __restrict__ c1_bf)
{
  __shared__ __align__(16) unsigned short inS[8 * 32 * 40];  // [row][x][ci pad40]
  int b = blockIdx.x / 5, s = blockIdx.x % 5;
  int y0 = s * 6;
  int tid = threadIdx.x, lane = tid & 63, w = tid >> 6;
  int li = lane & 15, cig8 = (lane >> 4) << 3;
  for (int uu = tid; uu < 1024; uu += 256) {
    int r = uu >> 7, rem = uu & 127;
    uint4 v = *reinterpret_cast<const uint4*>(
        &p_bf[((((size_t)b << 10) + (y0 + r) * 32) << 5) + rem * 8]);
    int xx = rem >> 2, cg = rem & 3;
    *reinterpret_cast<uint4*>(&inS[(r * 32 + xx) * 40 + cg * 8]) = v;
  }
  bf16x8 aw[9][2];
  #pragma unroll
  for (int t = 0; t < 9; t++)
    #pragma unroll
    for (int m = 0; m < 2; m++)
      aw[t][m] = *reinterpret_cast<const bf16x8*>(&Wf1[(((t << 1) + m) * 64 + lane) * 8]);
  float scv[2][4], sbv[2][4];
  #pragma unroll
  for (int m = 0; m < 2; m++)
    #pragma unroll
    for (int j = 0; j < 4; j++) {
      int co = m * 16 + ((lane >> 4) << 2) + j;
      float sc = g[co] * rsqrtf(vv[co] + 1e-5f);
      scv[m][j] = sc;
      sbv[m][j] = fmaf(cbias[co] - mm[co], sc, be[co]);
    }
  __syncthreads();
  #pragma unroll
  for (int q = 0; q < 3; q++) {
    int pf = w + q * 4;
    int p = pf * 16 + li;
    int pv = (p < 180) ? p : 0;
    int ry = pv / 30, rx = pv % 30;
    f32x4 a0 = {0.f, 0.f, 0.f, 0.f}, a1 = {0.f, 0.f, 0.f, 0.f};
    #pragma unroll
    for (int t = 0; t < 9; t++) {
      int dy = t / 3, dx = t % 3;
      bf16x8 bfr = *reinterpret_cast<const bf16x8*>(
          &inS[((ry + dy) * 32 + rx + dx) * 40 + cig8]);
      a0 = MFMA16(aw[t][0], bfr, a0);
      a1 = MFMA16(aw[t][1], bfr, a1);
    }
    if (p < 180) {
      size_t obase = ((size_t)b * 900 + (size_t)(y0 + ry) * 30 + rx) << 5;
      #pragma unroll
      for (int m = 0; m < 2; m++) {
        f32x4 av = m ? a1 : a0;
        ushort4 pk;
        pk.x = f2bf(fmaxf(fmaf(av[0], scv[m][0], sbv[m][0]), 0.f));
        pk.y = f2bf(fmaxf(fmaf(av[1], scv[m][1], sbv[m][1]), 0.f));
        pk.z = f2bf(fmaxf(fmaf(av[2], scv[m][2], sbv[m][2]), 0.f));
        pk.w = f2bf(fmaxf(fmaf(av[3], scv[m][3], sbv[m][3]), 0.f));
        *reinterpret_cast<ushort4*>(&c1_bf[obase + m * 16 + ((lane >> 4) << 2)]) = pk;
      }
    }
  }
}

// ---------------- K3b: conv2 3x3 VALID (32->128) + BN2 + ReLU + spatial-sum, MFMA --------
__global__ __launch_bounds__(256) void k_conv2m(
    const unsigned short* __restrict__ c1_bf, const unsigned short* __restrict__ Wf2,
    const float* __restrict__ cb2,
    const float* __restrict__ g, const float* __restrict__ be,
    const float* __restrict__ mm, const float* __restrict__ vv,
    float* __restrict__ cnn_sum)
{
  __shared__ __align__(16) unsigned short inS[6 * 30 * 40];
  int b = blockIdx.x / 7, s = blockIdx.x % 7;
  int y0 = s * 4;
  int tid = threadIdx.x, lane = tid & 63, w = tid >> 6;
  int li = lane & 15, cig8 = (lane >> 4) << 3;
  for (int uu = tid; uu < 720; uu += 256) {
    int r = uu / 120, rem = uu % 120;
    uint4 v = *reinterpret_cast<const uint4*>(
        &c1_bf[(((size_t)b * 900 + (size_t)(y0 + r) * 30) << 5) + rem * 8]);
    int xx = rem >> 2, cg = rem & 3;
    *reinterpret_cast<uint4*>(&inS[(r * 30 + xx) * 40 + cg * 8]) = v;
  }
  bf16x8 aw[9][2];
  #pragma unroll
  for (int t = 0; t < 9; t++)
    #pragma unroll
    for (int m = 0; m < 2; m++)
      aw[t][m] = *reinterpret_cast<const bf16x8*>(&Wf2[(((t << 3) + (w << 1) + m) * 64 + lane) * 8]);
  float scv[2][4], sbv[2][4];
  float psum[2][4] = {{0.f,0.f,0.f,0.f},{0.f,0.f,0.f,0.f}};
  #pragma unroll
  for (int m = 0; m < 2; m++)
    #pragma unroll
    for (int j = 0; j < 4; j++) {
      int co = (w << 5) + m * 16 + ((lane >> 4) << 2) + j;
      float sc = g[co] * rsqrtf(vv[co] + 1e-5f);
      scv[m][j] = sc;
      sbv[m][j] = fmaf(cb2[co] - mm[co], sc, be[co]);
    }
  __syncthreads();
  #pragma unroll
  for (int pf = 0; pf < 7; pf++) {
    int p = pf * 16 + li;
    int ry = p / 28, rx = p % 28;
    f32x4 a0 = {0.f, 0.f, 0.f, 0.f}, a1 = {0.f, 0.f, 0.f, 0.f};
    #pragma unroll
    for (int t = 0; t < 9; t++) {
      int dy = t / 3, dx = t % 3;
      bf16x8 bfr = *reinterpret_cast<const bf16x8*>(
          &inS[((ry + dy) * 30 + rx + dx) * 40 + cig8]);
      a0 = MFMA16(aw[t][0], bfr, a0);
      a1 = MFMA16(aw[t][1], bfr, a1);
    }
    #pragma unroll
    for (int j = 0; j < 4; j++) {
      psum[0][j] += fmaxf(fmaf(a0[j], scv[0][j], sbv[0][j]), 0.f);
      psum[1][j] += fmaxf(fmaf(a1[j], scv[1][j], sbv[1][j]), 0.f);
    }
  }
  #pragma unroll
  for (int m = 0; m < 2; m++)
    #pragma unroll
    for (int j = 0; j < 4; j++) {
      float v = psum[m][j];
      v += __shfl_xor(v, 1); v += __shfl_xor(v, 2);
      v += __shfl_xor(v, 4); v += __shfl_xor(v, 8);
      if (li == 0) {
        int co = (w << 5) + m * 16 + ((lane >> 4) << 2) + j;
        atomicAdd(&cnn_sum[((size_t)b << 7) + co], v);
      }
    }
}

// ---------------- K4: out = ybar @ W2^T + fc_b + cnn_sum/784 ----------------
__global__ __launch_bounds__(256) void k_final(
    const float* __restrict__ ybar, const float* __restrict__ W2,
    const float* __restrict__ fc_b, const float* __restrict__ cnn_sum,
    float* __restrict__ out)
{
  int i = blockIdx.x * 256 + threadIdx.x;   // 16384
  int b = i >> 7, f = i & 127;
  float a = 0.f;
  #pragma unroll
  for (int d2 = 0; d2 < 64; d2++) a = fmaf(ybar[(b << 6) + d2], W2[(f << 6) + d2], a);
  out[i] = a + fc_b[f] + cnn_sum[i] * (1.f / 784.f);
}

extern "C" void kernel_launch(void* const* d_in, const int* in_sizes, int n_in,
                              void* d_out, int out_size, void* d_ws, size_t ws_size,
                              hipStream_t stream) {
  (void)in_sizes; (void)n_in; (void)out_size; (void)ws_size;
  const float* x         = (const float*)d_in[0];
  const float* proj_w    = (const float*)d_in[1];
  const float* proj_b    = (const float*)d_in[2];
  const float* bn0_g     = (const float*)d_in[3];
  const float* bn0_b     = (const float*)d_in[4];
  const float* bn0_m     = (const float*)d_in[5];
  const float* bn0_v     = (const float*)d_in[6];
  const float* in_proj_w = (const float*)d_in[7];
  const float* conv_w    = (const float*)d_in[8];
  const float* conv_b    = (const float*)d_in[9];
  const float* x_proj_w  = (const float*)d_in[10];
  const float* dt_w      = (const float*)d_in[11];
  const float* dt_b      = (const float*)d_in[12];
  const float* A_log     = (const float*)d_in[13];
  const float* Dp        = (const float*)d_in[14];
  const float* out_proj_w= (const float*)d_in[15];
  const float* fc_w      = (const float*)d_in[16];
  const float* fc_b      = (const float*)d_in[17];
  const float* c1_w      = (const float*)d_in[18];
  const float* c1_b      = (const float*)d_in[19];
  const float* bn1_g     = (const float*)d_in[20];
  const float* bn1_b     = (const float*)d_in[21];
  const float* bn1_m     = (const float*)d_in[22];
  const float* bn1_v     = (const float*)d_in[23];
  const float* c2_w      = (const float*)d_in[24];
  const float* c2_b      = (const float*)d_in[25];
  const float* bn2_g     = (const float*)d_in[26];
  const float* bn2_b     = (const float*)d_in[27];
  const float* bn2_m     = (const float*)d_in[28];
  const float* bn2_v     = (const float*)d_in[29];
  float* out = (float*)d_out;
  float* ws  = (float*)d_ws;
  // workspace layout (float slots); ~33 MB
  float* p_tok   = ws;                                       // 4194304
  float* ybar    = ws + 4194304;                             // 8192
  float* cnn_sum = ws + 4202496;                             // 16384
  float* W2      = ws + 4218880;                             // 8192
  unsigned short* p_bf  = (unsigned short*)(ws + 4227072);   // 4194304 bf16
  unsigned short* c1_bf = (unsigned short*)(ws + 6324224);   // 3686400 bf16
  unsigned short* Wf1   = (unsigned short*)(ws + 8167424);   // 9216 bf16
  unsigned short* Wf2   = (unsigned short*)(ws + 8172032);   // 36864 bf16

  k_prep<<<dim3(276), dim3(256), 0, stream>>>(c1_w, c2_w, fc_w, out_proj_w, Wf1, Wf2, W2, cnn_sum);
  k_proj_bn<<<dim3(512), dim3(256), 0, stream>>>(x, proj_w, proj_b, bn0_g, bn0_b, bn0_m, bn0_v, p_tok, p_bf);
  k_mamba<<<dim3(256), dim3(512), 0, stream>>>(p_tok, in_proj_w, conv_w, conv_b, x_proj_w, dt_w, dt_b,
                                               A_log, Dp, ybar);
  k_conv1m<<<dim3(640), dim3(256), 0, stream>>>(p_bf, Wf1, c1_b, bn1_g, bn1_b, bn1_m, bn1_v, c1_bf);
  k_conv2m<<<dim3(896), dim3(256), 0, stream>>>(c1_bf, Wf2, c2_b, bn2_g, bn2_b, bn2_m, bn2_v, cnn_sum);
  k_final<<<dim3(64), dim3(256), 0, stream>>>(ybar, W2, fc_b, cnn_sum, out);
}

// Round 4
// 541.816 us; speedup vs baseline: 1.0092x; 1.0092x over previous
//
#include <hip/hip_runtime.h>
#include <cstdint>

typedef short bf16x8 __attribute__((ext_vector_type(8)));
typedef float f32x4 __attribute__((ext_vector_type(4)));
#define MFMA16(a, b, c) __builtin_amdgcn_mfma_f32_16x16x32_bf16((a), (b), (c), 0, 0, 0)

static __device__ __forceinline__ float sigmoidf_(float x) { return 1.f / (1.f + __expf(-x)); }
static __device__ __forceinline__ unsigned short f2bf(float f) {
  union { float f; unsigned u; } v; v.f = f;
  unsigned r = v.u + 0x7FFF + ((v.u >> 16) & 1);
  return (unsigned short)(r >> 16);
}

// ---------------- K0: weight prep (frag layouts for MFMA convs), W2, zero cnn_sum -------
__global__ __launch_bounds__(256) void k_prep(
    const float* __restrict__ c1_w, const float* __restrict__ c2_w,
    const float* __restrict__ fc_w, const float* __restrict__ opw,
    unsigned short* __restrict__ Wf1, unsigned short* __restrict__ Wf2,
    float* __restrict__ W2, float* __restrict__ cnn_sum)
{
  int i = blockIdx.x * 256 + threadIdx.x;
  if (i < 36864) {           // Wf2[t][cf 0..7][lane][j] = c2_w[co][ci][dy][dx]
    int j = i & 7, l = (i >> 3) & 63, m = (i >> 9) & 7, t = i >> 12;
    int co = m * 16 + (l & 15), ci = ((l >> 4) << 3) + j;
    Wf2[i] = f2bf(c2_w[(size_t)(co * 32 + ci) * 9 + t]);
  } else if (i < 46080) {    // Wf1[t][cf 0..1][lane][j]
    int ii = i - 36864;
    int j = ii & 7, l = (ii >> 3) & 63, m = (ii >> 9) & 1, t = ii >> 10;
    int co = m * 16 + (l & 15), ci = ((l >> 4) << 3) + j;
    Wf1[ii] = f2bf(c1_w[(size_t)(co * 32 + ci) * 9 + t]);
  } else if (i < 54272) {    // W2 = fc_w @ out_proj_w (128x64)
    int ii = i - 46080;
    int f = ii >> 6, d2 = ii & 63;
    float a = 0.f;
    #pragma unroll
    for (int dm = 0; dm < 32; dm++) a = fmaf(fc_w[(f << 5) + dm], opw[(dm << 6) + d2], a);
    W2[ii] = a;
  } else if (i < 70656) {
    cnn_sum[i - 54272] = 0.f;
  }
}

// ---------------- K1: 1x1 conv (proj) + BN0 + ReLU -> p_tok (f32), p_bf (bf16) ----------
__global__ __launch_bounds__(256) void k_proj_bn(
    const float* __restrict__ x, const float* __restrict__ w,
    const float* __restrict__ pb,
    const float* __restrict__ g, const float* __restrict__ be,
    const float* __restrict__ mm, const float* __restrict__ vv,
    float* __restrict__ p_tok, unsigned short* __restrict__ p_bf)
{
  __shared__ float wl[6400];        // [c][d] transposed proj_w
  __shared__ float sc[32], sb[32];
  int b = blockIdx.x >> 2, ch = blockIdx.x & 3;
  for (int i = threadIdx.x; i < 6400; i += 256) {
    int c = i >> 5, d = i & 31;
    wl[i] = w[d * 200 + c];
  }
  if (threadIdx.x < 32) {
    int d = threadIdx.x;
    float s = g[d] * rsqrtf(vv[d] + 1e-5f);
    sc[d] = s;
    sb[d] = fmaf(pb[d] - mm[d], s, be[d]);
  }
  __syncthreads();
  int l = (ch << 8) + threadIdx.x;
  const float* xp = x + (size_t)b * 200 * 1024 + l;
  float acc[32];
  #pragma unroll
  for (int d = 0; d < 32; d++) acc[d] = 0.f;
  for (int c = 0; c < 200; c++) {
    float xv = xp[(size_t)c << 10];
    const float* wr = &wl[c << 5];
    #pragma unroll
    for (int d = 0; d < 32; d++) acc[d] = fmaf(xv, wr[d], acc[d]);
  }
  #pragma unroll
  for (int d = 0; d < 32; d++) {
    float val = fmaf(acc[d], sc[d], sb[d]);
    acc[d] = fmaxf(val, 0.f);
  }
  float* pt = p_tok + (((size_t)b << 10) + l) * 32;
  #pragma unroll
  for (int d = 0; d < 32; d += 4)
    *reinterpret_cast<float4*>(pt + d) = make_float4(acc[d], acc[d+1], acc[d+2], acc[d+3]);
  unsigned short* pbf = p_bf + (((size_t)b << 10) + l) * 32;
  #pragma unroll
  for (int k = 0; k < 4; k++) {
    uint4 q;
    q.x = (unsigned)f2bf(acc[8*k+0]) | ((unsigned)f2bf(acc[8*k+1]) << 16);
    q.y = (unsigned)f2bf(acc[8*k+2]) | ((unsigned)f2bf(acc[8*k+3]) << 16);
    q.z = (unsigned)f2bf(acc[8*k+4]) | ((unsigned)f2bf(acc[8*k+5]) << 16);
    q.w = (unsigned)f2bf(acc[8*k+6]) | ((unsigned)f2bf(acc[8*k+7]) << 16);
    *reinterpret_cast<uint4*>(pbf + k * 8) = q;
  }
}

// ---------------- K2: FUSED mamba (in_proj -> dwconv -> x_proj -> softplus -> scan) -----
// grid 256 = (b, d-half); 512 threads; all weights persistent in regs (256-VGPR budget).
__global__ __launch_bounds__(512, 2) void k_mamba(
    const float* __restrict__ p_tok,
    const float* __restrict__ in_w,      // (128,32)
    const float* __restrict__ conv_w,    // (64,4)
    const float* __restrict__ conv_b,    // (64)
    const float* __restrict__ xp_w,      // (34,64)
    const float* __restrict__ dt_w,      // (64,2)
    const float* __restrict__ dt_b,      // (64)
    const float* __restrict__ A_log,     // (64,16)
    const float* __restrict__ Dp,        // (64)
    float* __restrict__ ybar)            // (128,64)
{
  __shared__ __align__(16) char smem[62256];
  float* xm   = (float*)smem;               // [67][68]  rows r = token t+3; rows 0..2 history
  float* dlS  = (float*)(smem + 816);       // [32][68]  alias xm rows 3..34 (delta, d-major)
  float* uS   = (float*)(smem + 18224);     // [64][68]  u, t-major (for x_proj)
  float* uT   = (float*)(smem + 35632);     // [32][68]  own-half u, d-major (for scan)
  float* zsT  = (float*)(smem + 44336);     // [32][68]  own-half silu(z), d-major
  float* bcT  = (float*)(smem + 53040);     // [32][68]  rows 0..15 B[n][t], 16..31 C[n][t]
  float* tokL = (float*)(smem + 53040);     // [67][32]  alias bcT (tokens, phase1 only)
  float* dt01 = (float*)(smem + 61744);     // [64][2]

  int b = blockIdx.x >> 1, hh = blockIdx.x & 1;
  int tid = threadIdx.x;

  // --- persistent per-role registers (intentionally hoisted; 256-VGPR budget) ---
  int p2d = tid & 63;                       // phase2 (dwconv) channel
  float4 cw4 = *reinterpret_cast<const float4*>(&conv_w[p2d << 2]);
  float cb1 = conv_b[p2d];
  int og = tid & 7;                         // dt01 o-slice
  float xw0[8], xw1[8];
  #pragma unroll
  for (int q = 0; q < 8; q++) {
    xw0[q] = xp_w[(og << 3) + q];
    xw1[q] = xp_w[64 + (og << 3) + q];
  }
  int dd = tid & 7;                         // phase4 d-group
  float dtw0[4], dtw1[4], dtb4[4];
  #pragma unroll
  for (int q = 0; q < 4; q++) {
    int dg = (hh << 5) + (dd << 2) + q;
    dtw0[q] = dt_w[2 * dg]; dtw1[q] = dt_w[2 * dg + 1]; dtb4[q] = dt_b[dg];
  }
  int p1o = tid & 127, p1tg = tid >> 7;     // phase1 (o, t-group)
  float4 w4[8];                             // phase1 weights (in_w row p1o)
  {
    const float* wr = &in_w[p1o << 5];
    #pragma unroll
    for (int c4 = 0; c4 < 8; c4++) w4[c4] = *reinterpret_cast<const float4*>(&wr[c4 << 2]);
  }
  int p3j = tid & 31, p3tg = tid >> 5;      // phase3 (j', t-group)
  float4 xw4[16];                           // phase3 weights (xp_w row 2+p3j)
  {
    const float* xwr = &xp_w[(2 + p3j) << 6];
    #pragma unroll
    for (int o4 = 0; o4 < 16; o4++) xw4[o4] = *reinterpret_cast<const float4*>(&xwr[o4 << 2]);
  }
  int sdl = tid >> 4, sn = tid & 15;        // scan (d_local, n)
  int sdg = (hh << 5) + sdl;
  float Areg = -__expf(A_log[(sdg << 4) + sn]);
  float hst = 0.f, acc_n = 0.f, acc_u = 0.f;

  const float* ptb = p_tok + ((size_t)b << 15);

  for (int ch = 0; ch < 16; ch++) {
    __syncthreads();                        // prev chunk's scan done
    // history rows + token staging (tokL aliases bcT — prev scan complete)
    if (tid < 192) {
      int r = tid >> 6, d = tid & 63;
      xm[r * 68 + d] = (ch == 0) ? 0.f : xm[(64 + r) * 68 + d];
    }
    for (int i = tid; i < 2144; i += 512) {
      int r = i >> 5, c = i & 31;
      int tg_ = (ch << 6) + r - 3;
      tokL[i] = (tg_ >= 0) ? ptb[(tg_ << 5) + c] : 0.f;
    }
    __syncthreads();                        // A
    // ---- phase1: xz = tok @ in_w^T (weights in regs, tok broadcast b128) ----
    {
      float accv[16];
      #pragma unroll
      for (int tt = 0; tt < 16; tt++) {
        const float* trow = &tokL[((p1tg << 4) + tt + 3) << 5];
        float a = 0.f;
        #pragma unroll
        for (int c4 = 0; c4 < 8; c4++) {
          float4 tv = *reinterpret_cast<const float4*>(&trow[c4 << 2]);
          a = fmaf(tv.x, w4[c4].x, a); a = fmaf(tv.y, w4[c4].y, a);
          a = fmaf(tv.z, w4[c4].z, a); a = fmaf(tv.w, w4[c4].w, a);
        }
        accv[tt] = a;
      }
      if (p1o < 64) {
        #pragma unroll
        for (int tt = 0; tt < 16; tt++)
          xm[((p1tg << 4) + tt + 3) * 68 + p1o] = accv[tt];
      } else {
        int dz = p1o - 64;
        if ((dz >> 5) == hh) {
          int dzl = dz & 31;
          #pragma unroll
          for (int tt = 0; tt < 16; tt++) {
            float a = accv[tt];
            zsT[dzl * 68 + (p1tg << 4) + tt] = a * sigmoidf_(a);
          }
        }
      }
    }
    __syncthreads();                        // B: xm, zsT ready
    // ---- phase2: causal dwconv(4) + silu -> uS (t-major), uT (own-half d-major) ----
    {
      int t0 = (tid >> 6) << 3;
      float x0 = xm[(t0 + 0) * 68 + p2d], x1 = xm[(t0 + 1) * 68 + p2d], x2 = xm[(t0 + 2) * 68 + p2d];
      bool own = (p2d >> 5) == hh;
      int dol = p2d & 31;
      #pragma unroll
      for (int s = 0; s < 8; s++) {
        int t = t0 + s;
        float x3 = xm[(t + 3) * 68 + p2d];
        float a = cb1;
        a = fmaf(cw4.x, x0, a); a = fmaf(cw4.y, x1, a);
        a = fmaf(cw4.z, x2, a); a = fmaf(cw4.w, x3, a);
        float uu = a * sigmoidf_(a);
        uS[t * 68 + p2d] = uu;
        if (own) uT[dol * 68 + t] = uu;
        x0 = x1; x1 = x2; x2 = x3;
      }
    }
    __syncthreads();                        // C: uS, uT ready
    // ---- phase3a: B/C = u @ xp_w[2:34]^T (weights in regs) -> bcT ----
    {
      #pragma unroll
      for (int s = 0; s < 4; s++) {
        int t = (p3tg << 2) + s;
        const float* ur = &uS[t * 68];
        float a = 0.f;
        #pragma unroll
        for (int o4 = 0; o4 < 16; o4++) {
          float4 uv = *reinterpret_cast<const float4*>(&ur[o4 << 2]);
          a = fmaf(uv.x, xw4[o4].x, a); a = fmaf(uv.y, xw4[o4].y, a);
          a = fmaf(uv.z, xw4[o4].z, a); a = fmaf(uv.w, xw4[o4].w, a);
        }
        bcT[p3j * 68 + t] = a;
      }
    }
    // ---- dt01: xdbl[:, 0:2] via 8-lane partial + shuffle reduce ----
    {
      int t = tid >> 3;
      const float* ur = &uS[t * 68 + (og << 3)];
      float4 ua = *reinterpret_cast<const float4*>(&ur[0]);
      float4 ub = *reinterpret_cast<const float4*>(&ur[4]);
      float a0 = 0.f, a1 = 0.f;
      a0 = fmaf(ua.x, xw0[0], a0); a0 = fmaf(ua.y, xw0[1], a0);
      a0 = fmaf(ua.z, xw0[2], a0); a0 = fmaf(ua.w, xw0[3], a0);
      a0 = fmaf(ub.x, xw0[4], a0); a0 = fmaf(ub.y, xw0[5], a0);
      a0 = fmaf(ub.z, xw0[6], a0); a0 = fmaf(ub.w, xw0[7], a0);
      a1 = fmaf(ua.x, xw1[0], a1); a1 = fmaf(ua.y, xw1[1], a1);
      a1 = fmaf(ua.z, xw1[2], a1); a1 = fmaf(ua.w, xw1[3], a1);
      a1 = fmaf(ub.x, xw1[4], a1); a1 = fmaf(ub.y, xw1[5], a1);
      a1 = fmaf(ub.z, xw1[6], a1); a1 = fmaf(ub.w, xw1[7], a1);
      a0 += __shfl_xor(a0, 1); a0 += __shfl_xor(a0, 2); a0 += __shfl_xor(a0, 4);
      a1 += __shfl_xor(a1, 1); a1 += __shfl_xor(a1, 2); a1 += __shfl_xor(a1, 4);
      if (og == 0) { dt01[t * 2] = a0; dt01[t * 2 + 1] = a1; }
    }
    __syncthreads();                        // D: bcT, dt01 ready
    // ---- phase4: delta = softplus(dt @ dt_w^T + dt_b) -> dlS (d-major, own half) ----
    {
      int t = tid >> 3;
      float d0 = dt01[t * 2], d1 = dt01[t * 2 + 1];
      #pragma unroll
      for (int q = 0; q < 4; q++) {
        float pre = fmaf(d0, dtw0[q], fmaf(d1, dtw1[q], dtb4[q]));
        float dl_ = (pre > 20.f) ? pre : log1pf(__expf(pre));
        dlS[((dd << 2) + q) * 68 + t] = dl_;
      }
    }
    __syncthreads();                        // E: dlS ready
    // ---- scan: 64 sequential steps, all float4 LDS reads ----
    {
      const float* dr = &dlS[sdl * 68];
      const float* ur = &uT[sdl * 68];
      const float* zr = &zsT[sdl * 68];
      const float* Br = &bcT[sn * 68];
      const float* Cr = &bcT[(16 + sn) * 68];
      for (int t = 0; t < 64; t += 4) {
        float4 dv = *reinterpret_cast<const float4*>(&dr[t]);
        float4 uv = *reinterpret_cast<const float4*>(&ur[t]);
        float4 zv = *reinterpret_cast<const float4*>(&zr[t]);
        float4 Bv = *reinterpret_cast<const float4*>(&Br[t]);
        float4 Cv = *reinterpret_cast<const float4*>(&Cr[t]);
        float e0 = __expf(dv.x * Areg), e1 = __expf(dv.y * Areg);
        float e2 = __expf(dv.z * Areg), e3 = __expf(dv.w * Areg);
        float k0 = dv.x * uv.x * Bv.x, k1 = dv.y * uv.y * Bv.y;
        float k2 = dv.z * uv.z * Bv.z, k3 = dv.w * uv.w * Bv.w;
        float c0 = Cv.x * zv.x, c1 = Cv.y * zv.y;
        float c2 = Cv.z * zv.z, c3 = Cv.w * zv.w;
        hst = fmaf(e0, hst, k0); acc_n = fmaf(hst, c0, acc_n);
        hst = fmaf(e1, hst, k1); acc_n = fmaf(hst, c1, acc_n);
        hst = fmaf(e2, hst, k2); acc_n = fmaf(hst, c2, acc_n);
        hst = fmaf(e3, hst, k3); acc_n = fmaf(hst, c3, acc_n);
        acc_u = fmaf(uv.x, zv.x, acc_u); acc_u = fmaf(uv.y, zv.y, acc_u);
        acc_u = fmaf(uv.z, zv.z, acc_u); acc_u = fmaf(uv.w, zv.w, acc_u);
      }
    }
  }
  // reduce acc_n over n lanes
  float y = acc_n;
  y += __shfl_xor(y, 1); y += __shfl_xor(y, 2);
  y += __shfl_xor(y, 4); y += __shfl_xor(y, 8);
  if (sn == 0)
    ybar[(b << 6) + sdg] = (y + Dp[sdg] * acc_u) * (1.f / 1024.f);
}

// ---------------- K3a: conv1 3x3 VALID (32->32) + BN1 + ReLU, MFMA, -> c1_bf -------------
__global__ __launch_bounds__(256) void k_conv1m(
    const unsigned short* __restrict__ p_bf, const unsigned short* __restrict__ Wf1,
    const float* __restrict__ cbias,
    const float* __restrict__ g, const float* __restrict__ be,
    const float* __restrict__ mm, const float* __restrict__ vv,
    unsigned short* __restrict__ c1_bf)
{
  __shared__ __align__(16) unsigned short inS[8 * 32 * 40];  // [row][x][ci pad40]
  int b = blockIdx.x / 5, s = blockIdx.x % 5;
  int y0 = s * 6;
  int tid = threadIdx.x, lane = tid & 63, w = tid >> 6;
  int li = lane & 15, cig8 = (lane >> 4) << 3;
  for (int uu = tid; uu < 1024; uu += 256) {
    int r = uu >> 7, rem = uu & 127;
    uint4 v = *reinterpret_cast<const uint4*>(
        &p_bf[((((size_t)b << 10) + (y0 + r) * 32) << 5) + rem * 8]);
    int xx = rem >> 2, cg = rem & 3;
    *reinterpret_cast<uint4*>(&inS[(r * 32 + xx) * 40 + cg * 8]) = v;
  }
  bf16x8 aw[9][2];
  #pragma unroll
  for (int t = 0; t < 9; t++)
    #pragma unroll
    for (int m = 0; m < 2; m++)
      aw[t][m] = *reinterpret_cast<const bf16x8*>(&Wf1[(((t << 1) + m) * 64 + lane) * 8]);
  float scv[2][4], sbv[2][4];
  #pragma unroll
  for (int m = 0; m < 2; m++)
    #pragma unroll
    for (int j = 0; j < 4; j++) {
      int co = m * 16 + ((lane >> 4) << 2) + j;
      float sc = g[co] * rsqrtf(vv[co] + 1e-5f);
      scv[m][j] = sc;
      sbv[m][j] = fmaf(cbias[co] - mm[co], sc, be[co]);
    }
  __syncthreads();
  #pragma unroll
  for (int q = 0; q < 3; q++) {
    int pf = w + q * 4;
    int p = pf * 16 + li;
    int pv = (p < 180) ? p : 0;
    int ry = pv / 30, rx = pv % 30;
    f32x4 a0 = {0.f, 0.f, 0.f, 0.f}, a1 = {0.f, 0.f, 0.f, 0.f};
    #pragma unroll
    for (int t = 0; t < 9; t++) {
      int dy = t / 3, dx = t % 3;
      bf16x8 bfr = *reinterpret_cast<const bf16x8*>(
          &inS[((ry + dy) * 32 + rx + dx) * 40 + cig8]);
      a0 = MFMA16(aw[t][0], bfr, a0);
      a1 = MFMA16(aw[t][1], bfr, a1);
    }
    if (p < 180) {
      size_t obase = ((size_t)b * 900 + (size_t)(y0 + ry) * 30 + rx) << 5;
      #pragma unroll
      for (int m = 0; m < 2; m++) {
        f32x4 av = m ? a1 : a0;
        ushort4 pk;
        pk.x = f2bf(fmaxf(fmaf(av[0], scv[m][0], sbv[m][0]), 0.f));
        pk.y = f2bf(fmaxf(fmaf(av[1], scv[m][1], sbv[m][1]), 0.f));
        pk.z = f2bf(fmaxf(fmaf(av[2], scv[m][2], sbv[m][2]), 0.f));
        pk.w = f2bf(fmaxf(fmaf(av[3], scv[m][3], sbv[m][3]), 0.f));
        *reinterpret_cast<ushort4*>(&c1_bf[obase + m * 16 + ((lane >> 4) << 2)]) = pk;
      }
    }
  }
}

// ---------------- K3b: conv2 3x3 VALID (32->128) + BN2 + ReLU + spatial-sum, MFMA --------
__global__ __launch_bounds__(256) void k_conv2m(
    const unsigned short* __restrict__ c1_bf, const unsigned short* __restrict__ Wf2,
    const float* __restrict__ cb2,
    const float* __restrict__ g, const float* __restrict__ be,
    const float* __restrict__ mm, const float* __restrict__ vv,
    float* __restrict__ cnn_sum)
{
  __shared__ __align__(16) unsigned short inS[6 * 30 * 40];
  int b = blockIdx.x / 7, s = blockIdx.x % 7;
  int y0 = s * 4;
  int tid = threadIdx.x, lane = tid & 63, w = tid >> 6;
  int li = lane & 15, cig8 = (lane >> 4) << 3;
  for (int uu = tid; uu < 720; uu += 256) {
    int r = uu / 120, rem = uu % 120;
    uint4 v = *reinterpret_cast<const uint4*>(
        &c1_bf[(((size_t)b * 900 + (size_t)(y0 + r) * 30) << 5) + rem * 8]);
    int xx = rem >> 2, cg = rem & 3;
    *reinterpret_cast<uint4*>(&inS[(r * 30 + xx) * 40 + cg * 8]) = v;
  }
  bf16x8 aw[9][2];
  #pragma unroll
  for (int t = 0; t < 9; t++)
    #pragma unroll
    for (int m = 0; m < 2; m++)
      aw[t][m] = *reinterpret_cast<const bf16x8*>(&Wf2[(((t << 3) + (w << 1) + m) * 64 + lane) * 8]);
  float scv[2][4], sbv[2][4];
  float psum[2][4] = {{0.f,0.f,0.f,0.f},{0.f,0.f,0.f,0.f}};
  #pragma unroll
  for (int m = 0; m < 2; m++)
    #pragma unroll
    for (int j = 0; j < 4; j++) {
      int co = (w << 5) + m * 16 + ((lane >> 4) << 2) + j;
      float sc = g[co] * rsqrtf(vv[co] + 1e-5f);
      scv[m][j] = sc;
      sbv[m][j] = fmaf(cb2[co] - mm[co], sc, be[co]);
    }
  __syncthreads();
  #pragma unroll
  for (int pf = 0; pf < 7; pf++) {
    int p = pf * 16 + li;
    int ry = p / 28, rx = p % 28;
    f32x4 a0 = {0.f, 0.f, 0.f, 0.f}, a1 = {0.f, 0.f, 0.f, 0.f};
    #pragma unroll
    for (int t = 0; t < 9; t++) {
      int dy = t / 3, dx = t % 3;
      bf16x8 bfr = *reinterpret_cast<const bf16x8*>(
          &inS[((ry + dy) * 30 + rx + dx) * 40 + cig8]);
      a0 = MFMA16(aw[t][0], bfr, a0);
      a1 = MFMA16(aw[t][1], bfr, a1);
    }
    #pragma unroll
    for (int j = 0; j < 4; j++) {
      psum[0][j] += fmaxf(fmaf(a0[j], scv[0][j], sbv[0][j]), 0.f);
      psum[1][j] += fmaxf(fmaf(a1[j], scv[1][j], sbv[1][j]), 0.f);
    }
  }
  #pragma unroll
  for (int m = 0; m < 2; m++)
    #pragma unroll
    for (int j = 0; j < 4; j++) {
      float v = psum[m][j];
      v += __shfl_xor(v, 1); v += __shfl_xor(v, 2);
      v += __shfl_xor(v, 4); v += __shfl_xor(v, 8);
      if (li == 0) {
        int co = (w << 5) + m * 16 + ((lane >> 4) << 2) + j;
        atomicAdd(&cnn_sum[((size_t)b << 7) + co], v);
      }
    }
}

// ---------------- K4: out = ybar @ W2^T + fc_b + cnn_sum/784 ----------------
__global__ __launch_bounds__(256) void k_final(
    const float* __restrict__ ybar, const float* __restrict__ W2,
    const float* __restrict__ fc_b, const float* __restrict__ cnn_sum,
    float* __restrict__ out)
{
  int i = blockIdx.x * 256 + threadIdx.x;   // 16384
  int b = i >> 7, f = i & 127;
  float a = 0.f;
  #pragma unroll
  for (int d2 = 0; d2 < 64; d2++) a = fmaf(ybar[(b << 6) + d2], W2[(f << 6) + d2], a);
  out[i] = a + fc_b[f] + cnn_sum[i] * (1.f / 784.f);
}

extern "C" void kernel_launch(void* const* d_in, const int* in_sizes, int n_in,
                              void* d_out, int out_size, void* d_ws, size_t ws_size,
                              hipStream_t stream) {
  (void)in_sizes; (void)n_in; (void)out_size; (void)ws_size;
  const float* x         = (const float*)d_in[0];
  const float* proj_w    = (const float*)d_in[1];
  const float* proj_b    = (const float*)d_in[2];
  const float* bn0_g     = (const float*)d_in[3];
  const float* bn0_b     = (const float*)d_in[4];
  const float* bn0_m     = (const float*)d_in[5];
  const float* bn0_v     = (const float*)d_in[6];
  const float* in_proj_w = (const float*)d_in[7];
  const float* conv_w    = (const float*)d_in[8];
  const float* conv_b    = (const float*)d_in[9];
  const float* x_proj_w  = (const float*)d_in[10];
  const float* dt_w      = (const float*)d_in[11];
  const float* dt_b      = (const float*)d_in[12];
  const float* A_log     = (const float*)d_in[13];
  const float* Dp        = (const float*)d_in[14];
  const float* out_proj_w= (const float*)d_in[15];
  const float* fc_w      = (const float*)d_in[16];
  const float* fc_b      = (const float*)d_in[17];
  const float* c1_w      = (const float*)d_in[18];
  const float* c1_b      = (const float*)d_in[19];
  const float* bn1_g     = (const float*)d_in[20];
  const float* bn1_b     = (const float*)d_in[21];
  const float* bn1_m     = (const float*)d_in[22];
  const float* bn1_v     = (const float*)d_in[23];
  const float* c2_w      = (const float*)d_in[24];
  const float* c2_b      = (const float*)d_in[25];
  const float* bn2_g     = (const float*)d_in[26];
  const float* bn2_b     = (const float*)d_in[27];
  const float* bn2_m     = (const float*)d_in[28];
  const float* bn2_v     = (const float*)d_in[29];
  float* out = (float*)d_out;
  float* ws  = (float*)d_ws;
  // workspace layout (float slots); ~33 MB
  float* p_tok   = ws;                                       // 4194304
  float* ybar    = ws + 4194304;                             // 8192
  float* cnn_sum = ws + 4202496;                             // 16384
  float* W2      = ws + 4218880;                             // 8192
  unsigned short* p_bf  = (unsigned short*)(ws + 4227072);   // 4194304 bf16
  unsigned short* c1_bf = (unsigned short*)(ws + 6324224);   // 3686400 bf16
  unsigned short* Wf1   = (unsigned short*)(ws + 8167424);   // 9216 bf16
  unsigned short* Wf2   = (unsigned short*)(ws + 8172032);   // 36864 bf16

  k_prep<<<dim3(276), dim3(256), 0, stream>>>(c1_w, c2_w, fc_w, out_proj_w, Wf1, Wf2, W2, cnn_sum);
  k_proj_bn<<<dim3(512), dim3(256), 0, stream>>>(x, proj_w, proj_b, bn0_g, bn0_b, bn0_m, bn0_v, p_tok, p_bf);
  k_mamba<<<dim3(256), dim3(512), 0, stream>>>(p_tok, in_proj_w, conv_w, conv_b, x_proj_w, dt_w, dt_b,
                                               A_log, Dp, ybar);
  k_conv1m<<<dim3(640), dim3(256), 0, stream>>>(p_bf, Wf1, c1_b, bn1_g, bn1_b, bn1_m, bn1_v, c1_bf);
  k_conv2m<<<dim3(896), dim3(256), 0, stream>>>(c1_bf, Wf2, c2_b, bn2_g, bn2_b, bn2_m, bn2_v, cnn_sum);
  k_final<<<dim3(64), dim3(256), 0, stream>>>(ybar, W2, fc_b, cnn_sum, out);
}

// Round 5
// 283.818 us; speedup vs baseline: 1.9265x; 1.9090x over previous
//
#include <hip/hip_runtime.h>
#include <cstdint>

typedef short bf16x8 __attribute__((ext_vector_type(8)));
typedef float f32x4 __attribute__((ext_vector_type(4)));
#define MFMA16(a, b, c) __builtin_amdgcn_mfma_f32_16x16x32_bf16((a), (b), (c), 0, 0, 0)

static __device__ __forceinline__ float sigmoidf_(float x) { return 1.f / (1.f + __expf(-x)); }
static __device__ __forceinline__ unsigned short f2bf(float f) {
  union { float f; unsigned u; } v; v.f = f;
  unsigned r = v.u + 0x7FFF + ((v.u >> 16) & 1);
  return (unsigned short)(r >> 16);
}

// ---------------- K0: weight prep (frag layouts for MFMA convs), W2, zero cnn_sum -------
__global__ __launch_bounds__(256) void k_prep(
    const float* __restrict__ c1_w, const float* __restrict__ c2_w,
    const float* __restrict__ fc_w, const float* __restrict__ opw,
    unsigned short* __restrict__ Wf1, unsigned short* __restrict__ Wf2,
    float* __restrict__ W2, float* __restrict__ cnn_sum)
{
  int i = blockIdx.x * 256 + threadIdx.x;
  if (i < 36864) {           // Wf2[t][cf 0..7][lane][j] = c2_w[co][ci][dy][dx]
    int j = i & 7, l = (i >> 3) & 63, m = (i >> 9) & 7, t = i >> 12;
    int co = m * 16 + (l & 15), ci = ((l >> 4) << 3) + j;
    Wf2[i] = f2bf(c2_w[(size_t)(co * 32 + ci) * 9 + t]);
  } else if (i < 46080) {    // Wf1[t][cf 0..1][lane][j]
    int ii = i - 36864;
    int j = ii & 7, l = (ii >> 3) & 63, m = (ii >> 9) & 1, t = ii >> 10;
    int co = m * 16 + (l & 15), ci = ((l >> 4) << 3) + j;
    Wf1[ii] = f2bf(c1_w[(size_t)(co * 32 + ci) * 9 + t]);
  } else if (i < 54272) {    // W2 = fc_w @ out_proj_w (128x64)
    int ii = i - 46080;
    int f = ii >> 6, d2 = ii & 63;
    float a = 0.f;
    #pragma unroll
    for (int dm = 0; dm < 32; dm++) a = fmaf(fc_w[(f << 5) + dm], opw[(dm << 6) + d2], a);
    W2[ii] = a;
  } else if (i < 70656) {
    cnn_sum[i - 54272] = 0.f;
  }
}

// ---------------- K1: 1x1 conv (proj) + BN0 + ReLU -> p_tok (f32), p_bf (bf16) ----------
__global__ __launch_bounds__(256) void k_proj_bn(
    const float* __restrict__ x, const float* __restrict__ w,
    const float* __restrict__ pb,
    const float* __restrict__ g, const float* __restrict__ be,
    const float* __restrict__ mm, const float* __restrict__ vv,
    float* __restrict__ p_tok, unsigned short* __restrict__ p_bf)
{
  __shared__ float wl[6400];        // [c][d] transposed proj_w
  __shared__ float sc[32], sb[32];
  int b = blockIdx.x >> 2, ch = blockIdx.x & 3;
  for (int i = threadIdx.x; i < 6400; i += 256) {
    int c = i >> 5, d = i & 31;
    wl[i] = w[d * 200 + c];
  }
  if (threadIdx.x < 32) {
    int d = threadIdx.x;
    float s = g[d] * rsqrtf(vv[d] + 1e-5f);
    sc[d] = s;
    sb[d] = fmaf(pb[d] - mm[d], s, be[d]);
  }
  __syncthreads();
  int l = (ch << 8) + threadIdx.x;
  const float* xp = x + (size_t)b * 200 * 1024 + l;
  float acc[32];
  #pragma unroll
  for (int d = 0; d < 32; d++) acc[d] = 0.f;
  for (int c = 0; c < 200; c++) {
    float xv = xp[(size_t)c << 10];
    const float* wr = &wl[c << 5];
    #pragma unroll
    for (int d = 0; d < 32; d++) acc[d] = fmaf(xv, wr[d], acc[d]);
  }
  #pragma unroll
  for (int d = 0; d < 32; d++) {
    float val = fmaf(acc[d], sc[d], sb[d]);
    acc[d] = fmaxf(val, 0.f);
  }
  float* pt = p_tok + (((size_t)b << 10) + l) * 32;
  #pragma unroll
  for (int d = 0; d < 32; d += 4)
    *reinterpret_cast<float4*>(pt + d) = make_float4(acc[d], acc[d+1], acc[d+2], acc[d+3]);
  unsigned short* pbf = p_bf + (((size_t)b << 10) + l) * 32;
  #pragma unroll
  for (int k = 0; k < 4; k++) {
    uint4 q;
    q.x = (unsigned)f2bf(acc[8*k+0]) | ((unsigned)f2bf(acc[8*k+1]) << 16);
    q.y = (unsigned)f2bf(acc[8*k+2]) | ((unsigned)f2bf(acc[8*k+3]) << 16);
    q.z = (unsigned)f2bf(acc[8*k+4]) | ((unsigned)f2bf(acc[8*k+5]) << 16);
    q.w = (unsigned)f2bf(acc[8*k+6]) | ((unsigned)f2bf(acc[8*k+7]) << 16);
    *reinterpret_cast<uint4*>(pbf + k * 8) = q;
  }
}

// ---------------- K2: FUSED mamba (in_proj -> dwconv -> x_proj -> softplus -> scan) -----
// grid 256 = (b, d-half); 512 threads. Register plan: persistent weights limited to
// w4 (32 v) + xw4h (32 v); all small weights staged in LDS and re-read per chunk
// (loads can't be LICM-hoisted across __syncthreads) => fits 128 VGPR, no scratch.
__global__ __launch_bounds__(512, 2) void k_mamba(
    const float* __restrict__ p_tok,
    const float* __restrict__ in_w,      // (128,32)
    const float* __restrict__ conv_w,    // (64,4)
    const float* __restrict__ conv_b,    // (64)
    const float* __restrict__ xp_w,      // (34,64)
    const float* __restrict__ dt_w,      // (64,2)
    const float* __restrict__ dt_b,      // (64)
    const float* __restrict__ A_log,     // (64,16)
    const float* __restrict__ Dp,        // (64)
    float* __restrict__ ybar)            // (128,64)
{
  __shared__ __align__(16) char smem[64816];
  float* xm   = (float*)smem;               // [67][68]  rows r = token t+3; rows 0..2 history
  float* dlS  = (float*)(smem + 816);       // [32][68]  alias xm rows 3..34 (delta, d-major)
  float* uS   = (float*)(smem + 18224);     // [64][68]  u, t-major (for x_proj)
  float* uT   = (float*)(smem + 35632);     // [32][68]  own-half u, d-major (for scan)
  float* zsT  = (float*)(smem + 44336);     // [32][68]  own-half silu(z), d-major
  float* bcT  = (float*)(smem + 53040);     // [32][68]  rows 0..15 B[n][t], 16..31 C[n][t]
  float* tokL = (float*)(smem + 53040);     // [67][32]  alias bcT (tokens, phase1 only)
  float* dt01 = (float*)(smem + 61744);     // [64][2]
  float* cwS  = (float*)(smem + 62256);     // [64][4]
  float* cbS  = (float*)(smem + 63280);     // [64]
  float* dtwS = (float*)(smem + 63536);     // [64][2]
  float* dtbS = (float*)(smem + 64048);     // [64]
  float* xw01S= (float*)(smem + 64304);     // [2][64]

  int b = blockIdx.x >> 1, hh = blockIdx.x & 1;
  int tid = threadIdx.x;

  // ---- stage small weights into LDS (once) ----
  if (tid < 256) cwS[tid] = conv_w[tid];
  else if (tid < 320) cbS[tid - 256] = conv_b[tid - 256];
  else if (tid < 448) dtwS[tid - 320] = dt_w[tid - 320];
  else if (tid < 512) dtbS[tid - 448] = dt_b[tid - 448];
  if (tid < 128) xw01S[tid] = xp_w[tid];

  // ---- role indices ----
  int p1o = tid & 127, p1tg = tid >> 7;     // phase1: output col, t-group (16 t each)
  int p2d = tid & 63;                       // phase2 channel
  int p3j = tid & 31;                       // phase3 output col (B/C j')
  int p3h = (tid >> 5) & 1;                 // phase3 K-half
  int p3tg = tid >> 6;                      // phase3 t-group (8 t each)
  int og = tid & 7;                         // dt01 o-slice
  int dd = tid & 7;                         // phase4 d-group
  int sdl = tid >> 4, sn = tid & 15;        // scan (d_local, n)
  int sdg = (hh << 5) + sdl;

  // ---- persistent weights (intentionally hoisted; 64 VGPRs total) ----
  float4 w4[8];                             // phase1: in_w row p1o
  {
    const float* wr = &in_w[p1o << 5];
    #pragma unroll
    for (int c4 = 0; c4 < 8; c4++) w4[c4] = *reinterpret_cast<const float4*>(&wr[c4 << 2]);
  }
  float4 xw4h[8];                           // phase3: xp_w row 2+p3j, K-half p3h
  {
    const float* xwr = &xp_w[((2 + p3j) << 6) + (p3h << 5)];
    #pragma unroll
    for (int o4 = 0; o4 < 8; o4++) xw4h[o4] = *reinterpret_cast<const float4*>(&xwr[o4 << 2]);
  }
  float Areg = -__expf(A_log[(sdg << 4) + sn]);
  float hst = 0.f, acc_n = 0.f, acc_u = 0.f;

  const float* ptb = p_tok + ((size_t)b << 15);

  for (int ch = 0; ch < 16; ch++) {
    __syncthreads();                        // prev chunk's scan done (also covers prologue)
    if (tid < 192) {
      int r = tid >> 6, d = tid & 63;
      xm[r * 68 + d] = (ch == 0) ? 0.f : xm[(64 + r) * 68 + d];
    }
    for (int i = tid; i < 2144; i += 512) {
      int r = i >> 5, c = i & 31;
      int tg_ = (ch << 6) + r - 3;
      tokL[i] = (tg_ >= 0) ? ptb[(tg_ << 5) + c] : 0.f;
    }
    __syncthreads();                        // A: tokL ready
    // ---- phase1: xz = tok @ in_w^T (weights in regs; write-through, no accv) ----
    {
      bool isx = (p1o < 64);
      int dz = p1o - 64;
      bool ownz = !isx && ((dz >> 5) == hh);
      int dzl = dz & 31;
      #pragma unroll
      for (int tt = 0; tt < 16; tt++) {
        const float* trow = &tokL[((p1tg << 4) + tt + 3) << 5];
        float a = 0.f;
        #pragma unroll
        for (int c4 = 0; c4 < 8; c4++) {
          float4 tv = *reinterpret_cast<const float4*>(&trow[c4 << 2]);
          a = fmaf(tv.x, w4[c4].x, a); a = fmaf(tv.y, w4[c4].y, a);
          a = fmaf(tv.z, w4[c4].z, a); a = fmaf(tv.w, w4[c4].w, a);
        }
        if (isx) xm[((p1tg << 4) + tt + 3) * 68 + p1o] = a;
        else if (ownz) zsT[dzl * 68 + (p1tg << 4) + tt] = a * sigmoidf_(a);
      }
    }
    __syncthreads();                        // B: xm, zsT ready
    // ---- phase2: causal dwconv(4) + silu -> uS (t-major), uT (own-half d-major) ----
    {
      float4 cw4 = *reinterpret_cast<const float4*>(&cwS[p2d << 2]);
      float cb1 = cbS[p2d];
      int t0 = (tid >> 6) << 3;
      float x0 = xm[(t0 + 0) * 68 + p2d], x1 = xm[(t0 + 1) * 68 + p2d], x2 = xm[(t0 + 2) * 68 + p2d];
      bool own = (p2d >> 5) == hh;
      int dol = p2d & 31;
      #pragma unroll
      for (int s = 0; s < 8; s++) {
        int t = t0 + s;
        float x3 = xm[(t + 3) * 68 + p2d];
        float a = cb1;
        a = fmaf(cw4.x, x0, a); a = fmaf(cw4.y, x1, a);
        a = fmaf(cw4.z, x2, a); a = fmaf(cw4.w, x3, a);
        float uu = a * sigmoidf_(a);
        uS[t * 68 + p2d] = uu;
        if (own) uT[dol * 68 + t] = uu;
        x0 = x1; x1 = x2; x2 = x3;
      }
    }
    __syncthreads();                        // C: uS, uT ready
    // ---- phase3: B/C = u @ xp_w[2:34]^T, K split across lane-pairs (xor 32) ----
    {
      #pragma unroll
      for (int s = 0; s < 8; s++) {
        int t = (p3tg << 3) + s;
        const float* ur = &uS[t * 68 + (p3h << 5)];
        float a = 0.f;
        #pragma unroll
        for (int o4 = 0; o4 < 8; o4++) {
          float4 uv = *reinterpret_cast<const float4*>(&ur[o4 << 2]);
          a = fmaf(uv.x, xw4h[o4].x, a); a = fmaf(uv.y, xw4h[o4].y, a);
          a = fmaf(uv.z, xw4h[o4].z, a); a = fmaf(uv.w, xw4h[o4].w, a);
        }
        a += __shfl_xor(a, 32);
        if (p3h == 0) bcT[p3j * 68 + t] = a;
      }
    }
    // ---- dt01: xdbl[:, 0:2] via 8-lane partial + shuffle reduce (weights from LDS) ----
    {
      int t = tid >> 3;
      float4 xwa0 = *reinterpret_cast<const float4*>(&xw01S[og << 3]);
      float4 xwb0 = *reinterpret_cast<const float4*>(&xw01S[(og << 3) + 4]);
      float4 xwa1 = *reinterpret_cast<const float4*>(&xw01S[64 + (og << 3)]);
      float4 xwb1 = *reinterpret_cast<const float4*>(&xw01S[64 + (og << 3) + 4]);
      const float* ur = &uS[t * 68 + (og << 3)];
      float4 ua = *reinterpret_cast<const float4*>(&ur[0]);
      float4 ub = *reinterpret_cast<const float4*>(&ur[4]);
      float a0 = 0.f, a1 = 0.f;
      a0 = fmaf(ua.x, xwa0.x, a0); a0 = fmaf(ua.y, xwa0.y, a0);
      a0 = fmaf(ua.z, xwa0.z, a0); a0 = fmaf(ua.w, xwa0.w, a0);
      a0 = fmaf(ub.x, xwb0.x, a0); a0 = fmaf(ub.y, xwb0.y, a0);
      a0 = fmaf(ub.z, xwb0.z, a0); a0 = fmaf(ub.w, xwb0.w, a0);
      a1 = fmaf(ua.x, xwa1.x, a1); a1 = fmaf(ua.y, xwa1.y, a1);
      a1 = fmaf(ua.z, xwa1.z, a1); a1 = fmaf(ua.w, xwa1.w, a1);
      a1 = fmaf(ub.x, xwb1.x, a1); a1 = fmaf(ub.y, xwb1.y, a1);
      a1 = fmaf(ub.z, xwb1.z, a1); a1 = fmaf(ub.w, xwb1.w, a1);
      a0 += __shfl_xor(a0, 1); a0 += __shfl_xor(a0, 2); a0 += __shfl_xor(a0, 4);
      a1 += __shfl_xor(a1, 1); a1 += __shfl_xor(a1, 2); a1 += __shfl_xor(a1, 4);
      if (og == 0) { dt01[t * 2] = a0; dt01[t * 2 + 1] = a1; }
    }
    __syncthreads();                        // D: bcT, dt01 ready
    // ---- phase4: delta = softplus(dt @ dt_w^T + dt_b) -> dlS (d-major, own half) ----
    {
      int t = tid >> 3;
      float d0 = dt01[t * 2], d1 = dt01[t * 2 + 1];
      #pragma unroll
      for (int q = 0; q < 4; q++) {
        int dg = (hh << 5) + (dd << 2) + q;
        float pre = fmaf(d0, dtwS[2 * dg], fmaf(d1, dtwS[2 * dg + 1], dtbS[dg]));
        float dl_ = (pre > 20.f) ? pre : log1pf(__expf(pre));
        dlS[((dd << 2) + q) * 68 + t] = dl_;
      }
    }
    __syncthreads();                        // E: dlS ready
    // ---- scan: 64 sequential steps, all float4 LDS reads ----
    {
      const float* dr = &dlS[sdl * 68];
      const float* ur = &uT[sdl * 68];
      const float* zr = &zsT[sdl * 68];
      const float* Br = &bcT[sn * 68];
      const float* Cr = &bcT[(16 + sn) * 68];
      for (int t = 0; t < 64; t += 4) {
        float4 dv = *reinterpret_cast<const float4*>(&dr[t]);
        float4 uv = *reinterpret_cast<const float4*>(&ur[t]);
        float4 zv = *reinterpret_cast<const float4*>(&zr[t]);
        float4 Bv = *reinterpret_cast<const float4*>(&Br[t]);
        float4 Cv = *reinterpret_cast<const float4*>(&Cr[t]);
        float e0 = __expf(dv.x * Areg), e1 = __expf(dv.y * Areg);
        float e2 = __expf(dv.z * Areg), e3 = __expf(dv.w * Areg);
        float k0 = dv.x * uv.x * Bv.x, k1 = dv.y * uv.y * Bv.y;
        float k2 = dv.z * uv.z * Bv.z, k3 = dv.w * uv.w * Bv.w;
        float c0 = Cv.x * zv.x, c1 = Cv.y * zv.y;
        float c2 = Cv.z * zv.z, c3 = Cv.w * zv.w;
        hst = fmaf(e0, hst, k0); acc_n = fmaf(hst, c0, acc_n);
        hst = fmaf(e1, hst, k1); acc_n = fmaf(hst, c1, acc_n);
        hst = fmaf(e2, hst, k2); acc_n = fmaf(hst, c2, acc_n);
        hst = fmaf(e3, hst, k3); acc_n = fmaf(hst, c3, acc_n);
        acc_u = fmaf(uv.x, zv.x, acc_u); acc_u = fmaf(uv.y, zv.y, acc_u);
        acc_u = fmaf(uv.z, zv.z, acc_u); acc_u = fmaf(uv.w, zv.w, acc_u);
      }
    }
  }
  // reduce acc_n over n lanes
  float y = acc_n;
  y += __shfl_xor(y, 1); y += __shfl_xor(y, 2);
  y += __shfl_xor(y, 4); y += __shfl_xor(y, 8);
  if (sn == 0)
    ybar[(b << 6) + sdg] = (y + Dp[sdg] * acc_u) * (1.f / 1024.f);
}

// ---------------- K3a: conv1 3x3 VALID (32->32) + BN1 + ReLU, MFMA, -> c1_bf -------------
__global__ __launch_bounds__(256) void k_conv1m(
    const unsigned short* __restrict__ p_bf, const unsigned short* __restrict__ Wf1,
    const float* __restrict__ cbias,
    const float* __restrict__ g, const float* __restrict__ be,
    const float* __restrict__ mm, const float* __restrict__ vv,
    unsigned short* __restrict__ c1_bf)
{
  __shared__ __align__(16) unsigned short inS[8 * 32 * 40];  // [row][x][ci pad40]
  int b = blockIdx.x / 5, s = blockIdx.x % 5;
  int y0 = s * 6;
  int tid = threadIdx.x, lane = tid & 63, w = tid >> 6;
  int li = lane & 15, cig8 = (lane >> 4) << 3;
  for (int uu = tid; uu < 1024; uu += 256) {
    int r = uu >> 7, rem = uu & 127;
    uint4 v = *reinterpret_cast<const uint4*>(
        &p_bf[((((size_t)b << 10) + (y0 + r) * 32) << 5) + rem * 8]);
    int xx = rem >> 2, cg = rem & 3;
    *reinterpret_cast<uint4*>(&inS[(r * 32 + xx) * 40 + cg * 8]) = v;
  }
  bf16x8 aw[9][2];
  #pragma unroll
  for (int t = 0; t < 9; t++)
    #pragma unroll
    for (int m = 0; m < 2; m++)
      aw[t][m] = *reinterpret_cast<const bf16x8*>(&Wf1[(((t << 1) + m) * 64 + lane) * 8]);
  float scv[2][4], sbv[2][4];
  #pragma unroll
  for (int m = 0; m < 2; m++)
    #pragma unroll
    for (int j = 0; j < 4; j++) {
      int co = m * 16 + ((lane >> 4) << 2) + j;
      float sc = g[co] * rsqrtf(vv[co] + 1e-5f);
      scv[m][j] = sc;
      sbv[m][j] = fmaf(cbias[co] - mm[co], sc, be[co]);
    }
  __syncthreads();
  #pragma unroll
  for (int q = 0; q < 3; q++) {
    int pf = w + q * 4;
    int p = pf * 16 + li;
    int pv = (p < 180) ? p : 0;
    int ry = pv / 30, rx = pv % 30;
    f32x4 a0 = {0.f, 0.f, 0.f, 0.f}, a1 = {0.f, 0.f, 0.f, 0.f};
    #pragma unroll
    for (int t = 0; t < 9; t++) {
      int dy = t / 3, dx = t % 3;
      bf16x8 bfr = *reinterpret_cast<const bf16x8*>(
          &inS[((ry + dy) * 32 + rx + dx) * 40 + cig8]);
      a0 = MFMA16(aw[t][0], bfr, a0);
      a1 = MFMA16(aw[t][1], bfr, a1);
    }
    if (p < 180) {
      size_t obase = ((size_t)b * 900 + (size_t)(y0 + ry) * 30 + rx) << 5;
      #pragma unroll
      for (int m = 0; m < 2; m++) {
        f32x4 av = m ? a1 : a0;
        ushort4 pk;
        pk.x = f2bf(fmaxf(fmaf(av[0], scv[m][0], sbv[m][0]), 0.f));
        pk.y = f2bf(fmaxf(fmaf(av[1], scv[m][1], sbv[m][1]), 0.f));
        pk.z = f2bf(fmaxf(fmaf(av[2], scv[m][2], sbv[m][2]), 0.f));
        pk.w = f2bf(fmaxf(fmaf(av[3], scv[m][3], sbv[m][3]), 0.f));
        *reinterpret_cast<ushort4*>(&c1_bf[obase + m * 16 + ((lane >> 4) << 2)]) = pk;
      }
    }
  }
}

// ---------------- K3b: conv2 3x3 VALID (32->128) + BN2 + ReLU + spatial-sum, MFMA --------
__global__ __launch_bounds__(256) void k_conv2m(
    const unsigned short* __restrict__ c1_bf, const unsigned short* __restrict__ Wf2,
    const float* __restrict__ cb2,
    const float* __restrict__ g, const float* __restrict__ be,
    const float* __restrict__ mm, const float* __restrict__ vv,
    float* __restrict__ cnn_sum)
{
  __shared__ __align__(16) unsigned short inS[6 * 30 * 40];
  int b = blockIdx.x / 7, s = blockIdx.x % 7;
  int y0 = s * 4;
  int tid = threadIdx.x, lane = tid & 63, w = tid >> 6;
  int li = lane & 15, cig8 = (lane >> 4) << 3;
  for (int uu = tid; uu < 720; uu += 256) {
    int r = uu / 120, rem = uu % 120;
    uint4 v = *reinterpret_cast<const uint4*>(
        &c1_bf[(((size_t)b * 900 + (size_t)(y0 + r) * 30) << 5) + rem * 8]);
    int xx = rem >> 2, cg = rem & 3;
    *reinterpret_cast<uint4*>(&inS[(r * 30 + xx) * 40 + cg * 8]) = v;
  }
  bf16x8 aw[9][2];
  #pragma unroll
  for (int t = 0; t < 9; t++)
    #pragma unroll
    for (int m = 0; m < 2; m++)
      aw[t][m] = *reinterpret_cast<const bf16x8*>(&Wf2[(((t << 3) + (w << 1) + m) * 64 + lane) * 8]);
  float scv[2][4], sbv[2][4];
  float psum[2][4] = {{0.f,0.f,0.f,0.f},{0.f,0.f,0.f,0.f}};
  #pragma unroll
  for (int m = 0; m < 2; m++)
    #pragma unroll
    for (int j = 0; j < 4; j++) {
      int co = (w << 5) + m * 16 + ((lane >> 4) << 2) + j;
      float sc = g[co] * rsqrtf(vv[co] + 1e-5f);
      scv[m][j] = sc;
      sbv[m][j] = fmaf(cb2[co] - mm[co], sc, be[co]);
    }
  __syncthreads();
  #pragma unroll
  for (int pf = 0; pf < 7; pf++) {
    int p = pf * 16 + li;
    int ry = p / 28, rx = p % 28;
    f32x4 a0 = {0.f, 0.f, 0.f, 0.f}, a1 = {0.f, 0.f, 0.f, 0.f};
    #pragma unroll
    for (int t = 0; t < 9; t++) {
      int dy = t / 3, dx = t % 3;
      bf16x8 bfr = *reinterpret_cast<const bf16x8*>(
          &inS[((ry + dy) * 30 + rx + dx) * 40 + cig8]);
      a0 = MFMA16(aw[t][0], bfr, a0);
      a1 = MFMA16(aw[t][1], bfr, a1);
    }
    #pragma unroll
    for (int j = 0; j < 4; j++) {
      psum[0][j] += fmaxf(fmaf(a0[j], scv[0][j], sbv[0][j]), 0.f);
      psum[1][j] += fmaxf(fmaf(a1[j], scv[1][j], sbv[1][j]), 0.f);
    }
  }
  #pragma unroll
  for (int m = 0; m < 2; m++)
    #pragma unroll
    for (int j = 0; j < 4; j++) {
      float v = psum[m][j];
      v += __shfl_xor(v, 1); v += __shfl_xor(v, 2);
      v += __shfl_xor(v, 4); v += __shfl_xor(v, 8);
      if (li == 0) {
        int co = (w << 5) + m * 16 + ((lane >> 4) << 2) + j;
        atomicAdd(&cnn_sum[((size_t)b << 7) + co], v);
      }
    }
}

// ---------------- K4: out = ybar @ W2^T + fc_b + cnn_sum/784 ----------------
__global__ __launch_bounds__(256) void k_final(
    const float* __restrict__ ybar, const float* __restrict__ W2,
    const float* __restrict__ fc_b, const float* __restrict__ cnn_sum,
    float* __restrict__ out)
{
  int i = blockIdx.x * 256 + threadIdx.x;   // 16384
  int b = i >> 7, f = i & 127;
  float a = 0.f;
  #pragma unroll
  for (int d2 = 0; d2 < 64; d2++) a = fmaf(ybar[(b << 6) + d2], W2[(f << 6) + d2], a);
  out[i] = a + fc_b[f] + cnn_sum[i] * (1.f / 784.f);
}

extern "C" void kernel_launch(void* const* d_in, const int* in_sizes, int n_in,
                              void* d_out, int out_size, void* d_ws, size_t ws_size,
                              hipStream_t stream) {
  (void)in_sizes; (void)n_in; (void)out_size; (void)ws_size;
  const float* x         = (const float*)d_in[0];
  const float* proj_w    = (const float*)d_in[1];
  const float* proj_b    = (const float*)d_in[2];
  const float* bn0_g     = (const float*)d_in[3];
  const float* bn0_b     = (const float*)d_in[4];
  const float* bn0_m     = (const float*)d_in[5];
  const float* bn0_v     = (const float*)d_in[6];
  const float* in_proj_w = (const float*)d_in[7];
  const float* conv_w    = (const float*)d_in[8];
  const float* conv_b    = (const float*)d_in[9];
  const float* x_proj_w  = (const float*)d_in[10];
  const float* dt_w      = (const float*)d_in[11];
  const float* dt_b      = (const float*)d_in[12];
  const float* A_log     = (const float*)d_in[13];
  const float* Dp        = (const float*)d_in[14];
  const float* out_proj_w= (const float*)d_in[15];
  const float* fc_w      = (const float*)d_in[16];
  const float* fc_b      = (const float*)d_in[17];
  const float* c1_w      = (const float*)d_in[18];
  const float* c1_b      = (const float*)d_in[19];
  const float* bn1_g     = (const float*)d_in[20];
  const float* bn1_b     = (const float*)d_in[21];
  const float* bn1_m     = (const float*)d_in[22];
  const float* bn1_v     = (const float*)d_in[23];
  const float* c2_w      = (const float*)d_in[24];
  const float* c2_b      = (const float*)d_in[25];
  const float* bn2_g     = (const float*)d_in[26];
  const float* bn2_b     = (const float*)d_in[27];
  const float* bn2_m     = (const float*)d_in[28];
  const float* bn2_v     = (const float*)d_in[29];
  float* out = (float*)d_out;
  float* ws  = (float*)d_ws;
  // workspace layout (float slots); ~33 MB
  float* p_tok   = ws;                                       // 4194304
  float* ybar    = ws + 4194304;                             // 8192
  float* cnn_sum = ws + 4202496;                             // 16384
  float* W2      = ws + 4218880;                             // 8192
  unsigned short* p_bf  = (unsigned short*)(ws + 4227072);   // 4194304 bf16
  unsigned short* c1_bf = (unsigned short*)(ws + 6324224);   // 3686400 bf16
  unsigned short* Wf1   = (unsigned short*)(ws + 8167424);   // 9216 bf16
  unsigned short* Wf2   = (unsigned short*)(ws + 8172032);   // 36864 bf16

  k_prep<<<dim3(276), dim3(256), 0, stream>>>(c1_w, c2_w, fc_w, out_proj_w, Wf1, Wf2, W2, cnn_sum);
  k_proj_bn<<<dim3(512), dim3(256), 0, stream>>>(x, proj_w, proj_b, bn0_g, bn0_b, bn0_m, bn0_v, p_tok, p_bf);
  k_mamba<<<dim3(256), dim3(512), 0, stream>>>(p_tok, in_proj_w, conv_w, conv_b, x_proj_w, dt_w, dt_b,
                                               A_log, Dp, ybar);
  k_conv1m<<<dim3(640), dim3(256), 0, stream>>>(p_bf, Wf1, c1_b, bn1_g, bn1_b, bn1_m, bn1_v, c1_bf);
  k_conv2m<<<dim3(896), dim3(256), 0, stream>>>(c1_bf, Wf2, c2_b, bn2_g, bn2_b, bn2_m, bn2_v, cnn_sum);
  k_final<<<dim3(64), dim3(256), 0, stream>>>(ybar, W2, fc_b, cnn_sum, out);
}

// Round 6
// 196.087 us; speedup vs baseline: 2.7885x; 1.4474x over previous
//
#include <hip/hip_runtime.h>
#include <cstdint>

typedef short bf16x8 __attribute__((ext_vector_type(8)));
typedef float f32x4 __attribute__((ext_vector_type(4)));
#define MFMA16(a, b, c) __builtin_amdgcn_mfma_f32_16x16x32_bf16((a), (b), (c), 0, 0, 0)

static __device__ __forceinline__ float sigmoidf_(float x) { return 1.f / (1.f + __expf(-x)); }
static __device__ __forceinline__ unsigned short f2bf(float f) {
  union { float f; unsigned u; } v; v.f = f;
  unsigned r = v.u + 0x7FFF + ((v.u >> 16) & 1);
  return (unsigned short)(r >> 16);
}

// ---------------- K0: weight prep (frag layouts), W2, zero cnn_sum ----------------------
__global__ __launch_bounds__(256) void k_prep(
    const float* __restrict__ c1_w, const float* __restrict__ c2_w,
    const float* __restrict__ fc_w, const float* __restrict__ opw,
    const float* __restrict__ in_w, const float* __restrict__ xp_w,
    unsigned short* __restrict__ Wf1, unsigned short* __restrict__ Wf2,
    unsigned short* __restrict__ Wfin, unsigned short* __restrict__ Wfxp,
    float* __restrict__ W2, float* __restrict__ cnn_sum)
{
  int i = blockIdx.x * 256 + threadIdx.x;
  if (i < 36864) {           // Wf2[t][cf 0..7][lane][j] = c2_w[co][ci][dy][dx]
    int j = i & 7, l = (i >> 3) & 63, m = (i >> 9) & 7, t = i >> 12;
    int co = m * 16 + (l & 15), ci = ((l >> 4) << 3) + j;
    Wf2[i] = f2bf(c2_w[(size_t)(co * 32 + ci) * 9 + t]);
  } else if (i < 46080) {    // Wf1[t][cf 0..1][lane][j]
    int ii = i - 36864;
    int j = ii & 7, l = (ii >> 3) & 63, m = (ii >> 9) & 1, t = ii >> 10;
    int co = m * 16 + (l & 15), ci = ((l >> 4) << 3) + j;
    Wf1[ii] = f2bf(c1_w[(size_t)(co * 32 + ci) * 9 + t]);
  } else if (i < 54272) {    // W2 = fc_w @ out_proj_w (128x64)
    int ii = i - 46080;
    int f = ii >> 6, d2 = ii & 63;
    float a = 0.f;
    #pragma unroll
    for (int dm = 0; dm < 32; dm++) a = fmaf(fc_w[(f << 5) + dm], opw[(dm << 6) + d2], a);
    W2[ii] = a;
  } else if (i < 70656) {
    cnn_sum[i - 54272] = 0.f;
  } else if (i < 74752) {    // Wfin[ot 0..7][lane][j] = in_w[o][c]
    int ii = i - 70656;
    int j = ii & 7, l = (ii >> 3) & 63, ot = ii >> 9;
    int o = (ot << 4) + (l & 15), c = ((l >> 4) << 3) + j;
    Wfin[ii] = f2bf(in_w[(o << 5) + c]);
  } else if (i < 77824) {    // Wfxp[ot 0..2][kh 0..1][lane][j] = xp_w[jr][c] (jr>=34 -> 0)
    int ii = i - 74752;
    int j = ii & 7, l = (ii >> 3) & 63, kh = (ii >> 9) & 1, ot = ii >> 10;
    int jr = (ot << 4) + (l & 15), c = (kh << 5) + ((l >> 4) << 3) + j;
    Wfxp[ii] = (jr < 34) ? f2bf(xp_w[(jr << 6) + c]) : (unsigned short)0;
  }
}

// ---------------- K1: 1x1 conv (proj) + BN0 + ReLU -> p_bf (bf16 tokens) ----------------
__global__ __launch_bounds__(256) void k_proj_bn(
    const float* __restrict__ x, const float* __restrict__ w,
    const float* __restrict__ pb,
    const float* __restrict__ g, const float* __restrict__ be,
    const float* __restrict__ mm, const float* __restrict__ vv,
    unsigned short* __restrict__ p_bf)
{
  __shared__ float wl[6400];        // [c][d] transposed proj_w
  __shared__ float sc[32], sb[32];
  int b = blockIdx.x >> 2, ch = blockIdx.x & 3;
  for (int i = threadIdx.x; i < 6400; i += 256) {
    int c = i >> 5, d = i & 31;
    wl[i] = w[d * 200 + c];
  }
  if (threadIdx.x < 32) {
    int d = threadIdx.x;
    float s = g[d] * rsqrtf(vv[d] + 1e-5f);
    sc[d] = s;
    sb[d] = fmaf(pb[d] - mm[d], s, be[d]);
  }
  __syncthreads();
  int l = (ch << 8) + threadIdx.x;
  const float* xp = x + (size_t)b * 200 * 1024 + l;
  float acc[32];
  #pragma unroll
  for (int d = 0; d < 32; d++) acc[d] = 0.f;
  for (int c = 0; c < 200; c++) {
    float xv = xp[(size_t)c << 10];
    const float* wr = &wl[c << 5];
    #pragma unroll
    for (int d = 0; d < 32; d++) acc[d] = fmaf(xv, wr[d], acc[d]);
  }
  #pragma unroll
  for (int d = 0; d < 32; d++) {
    float val = fmaf(acc[d], sc[d], sb[d]);
    acc[d] = fmaxf(val, 0.f);
  }
  unsigned short* pbf = p_bf + (((size_t)b << 10) + l) * 32;
  #pragma unroll
  for (int k = 0; k < 4; k++) {
    uint4 q;
    q.x = (unsigned)f2bf(acc[8*k+0]) | ((unsigned)f2bf(acc[8*k+1]) << 16);
    q.y = (unsigned)f2bf(acc[8*k+2]) | ((unsigned)f2bf(acc[8*k+3]) << 16);
    q.z = (unsigned)f2bf(acc[8*k+4]) | ((unsigned)f2bf(acc[8*k+5]) << 16);
    q.w = (unsigned)f2bf(acc[8*k+6]) | ((unsigned)f2bf(acc[8*k+7]) << 16);
    *reinterpret_cast<uint4*>(pbf + k * 8) = q;
  }
}

// ---------------- K2: FUSED mamba, MFMA for in_proj & x_proj; fp32 dwconv/softplus/scan --
// grid 256 = (b, d-half); 512 threads (8 waves). Wave w: phase1 o-tile w; phase3 jobs.
#define XM_OFF   0
#define UBF_OFF  18224
#define UT_OFF   27440
#define ZST_OFF  36144
#define BCT_OFF  44848
#define TOKL_OFF 53552
#define DT01_OFF 63200
#define CWS_OFF  63712
#define CBS_OFF  64736
#define DTW_OFF  64992
#define DTB_OFF  65504
__global__ __launch_bounds__(512, 2) void k_mamba(
    const unsigned short* __restrict__ p_bf,
    const unsigned short* __restrict__ Wfin,
    const unsigned short* __restrict__ Wfxp,
    const float* __restrict__ conv_w,    // (64,4)
    const float* __restrict__ conv_b,    // (64)
    const float* __restrict__ dt_w,      // (64,2)
    const float* __restrict__ dt_b,      // (64)
    const float* __restrict__ A_log,     // (64,16)
    const float* __restrict__ Dp,        // (64)
    float* __restrict__ ybar)            // (128,64)
{
  __shared__ __align__(16) char smem[65760];
  float* xm   = (float*)(smem + XM_OFF);      // [67][68] f32; rows 0..2 = history
  float* dlS  = (float*)(smem + XM_OFF + 816);// [32][68] alias xm rows 3..34
  unsigned short* ubS = (unsigned short*)(smem + UBF_OFF);  // [64][72] bf16 u
  float* uT   = (float*)(smem + UT_OFF);      // [32][68] own-half u (f32, d-major)
  float* zsT  = (float*)(smem + ZST_OFF);     // [32][68] own-half silu(z) (d-major)
  float* bcT  = (float*)(smem + BCT_OFF);     // [32][68] B rows 0..15, C rows 16..31
  float* dt01 = (float*)(smem + DT01_OFF);    // [64][2]
  float* cwS  = (float*)(smem + CWS_OFF);     // [64][4]
  float* cbS  = (float*)(smem + CBS_OFF);     // [64]
  float* dtwS = (float*)(smem + DTW_OFF);     // [64][2]
  float* dtbS = (float*)(smem + DTB_OFF);     // [64]

  int b = blockIdx.x >> 1, hh = blockIdx.x & 1;
  int tid = threadIdx.x;
  int lane = tid & 63, w = tid >> 6;
  int li = lane & 15, cig8 = (lane >> 4) << 3;

  // ---- stage small weights into LDS (once) ----
  if (tid < 256) cwS[tid] = conv_w[tid];
  else if (tid < 320) cbS[tid - 256] = conv_b[tid - 256];
  else if (tid < 448) dtwS[tid - 320] = dt_w[tid - 320];
  else if (tid < 512) dtbS[tid - 448] = dt_b[tid - 448];

  // ---- per-wave MFMA A-fragments (persistent, small) ----
  bf16x8 aWin = *reinterpret_cast<const bf16x8*>(&Wfin[((w << 6) + lane) << 3]);
  int otA = w >> 2, ttA = w & 3;
  bf16x8 xpa0 = *reinterpret_cast<const bf16x8*>(&Wfxp[(((otA << 1) + 0) * 64 + lane) << 3]);
  bf16x8 xpa1 = *reinterpret_cast<const bf16x8*>(&Wfxp[(((otA << 1) + 1) * 64 + lane) << 3]);
  bf16x8 xpb0 = *reinterpret_cast<const bf16x8*>(&Wfxp[((4) * 64 + lane) << 3]);
  bf16x8 xpb1 = *reinterpret_cast<const bf16x8*>(&Wfxp[((5) * 64 + lane) << 3]);

  // ---- per-role persistent state ----
  int p2d = lane;                           // phase2 channel (with w = t-octave)
  int dd = tid & 7;                         // phase4 d-group
  int sdl = tid >> 4, sn = tid & 15;        // scan (d_local, n)
  int sdg = (hh << 5) + sdl;
  float Areg = -__expf(A_log[(sdg << 4) + sn]);
  float hst = 0.f, acc_n = 0.f, acc_u = 0.f;
  bool zwave = (w >= 4);
  bool p1act = !zwave || (((w - 4) >> 1) == hh);
  int dzq = ((w - 4) << 4) + ((lane >> 4) << 2);

  const unsigned short* pbf_b = p_bf + ((size_t)b << 15);

  for (int ch = 0; ch < 16; ch++) {
    __syncthreads();                        // prev chunk's scan done (covers prologue too)
    // history rows 64..66 -> 0..2 ; stage 67 token rows (bf16, 64B each) into tokL
    if (tid < 192) {
      int r = tid >> 6, d = tid & 63;
      xm[r * 68 + d] = (ch == 0) ? 0.f : xm[(64 + r) * 68 + d];
    }
    for (int i = tid; i < 536; i += 512) {
      int r = i >> 3, sg = i & 7;
      int tg_ = (ch << 6) + r - 3;
      uint2 v = make_uint2(0u, 0u);
      if (tg_ >= 0)
        v = *reinterpret_cast<const uint2*>(pbf_b + ((size_t)tg_ << 5) + (sg << 2));
      *reinterpret_cast<uint2*>(smem + TOKL_OFF + r * 144 + (sg << 3)) = v;
    }
    __syncthreads();                        // A: tokens staged
    // ---- phase1 (MFMA): xz = in_w @ tok ; x -> xm rows 3..66 ; silu(z) -> zsT ----
    if (p1act) {
      #pragma unroll
      for (int tt = 0; tt < 4; tt++) {
        int t = (tt << 4) + li;
        bf16x8 bfr = *reinterpret_cast<const bf16x8*>(
            smem + TOKL_OFF + (t + 3) * 144 + (cig8 << 1));
        f32x4 acc = {0.f, 0.f, 0.f, 0.f};
        acc = MFMA16(aWin, bfr, acc);
        if (!zwave) {
          *reinterpret_cast<float4*>(&xm[(t + 3) * 68 + (w << 4) + ((lane >> 4) << 2)]) =
              make_float4(acc[0], acc[1], acc[2], acc[3]);
        } else {
          int dzl = dzq & 31;
          #pragma unroll
          for (int q = 0; q < 4; q++) {
            float zz = acc[q];
            zsT[(dzl + q) * 68 + t] = zz * sigmoidf_(zz);
          }
        }
      }
    }
    __syncthreads();                        // B: xm, zsT ready
    // ---- phase2: causal dwconv(4) + silu -> u_bf (bf16 t-major), uT (own-half f32) ----
    {
      float4 cw4 = *reinterpret_cast<const float4*>(&cwS[p2d << 2]);
      float cb1 = cbS[p2d];
      int t0 = w << 3;
      float x0 = xm[(t0 + 0) * 68 + p2d], x1 = xm[(t0 + 1) * 68 + p2d], x2 = xm[(t0 + 2) * 68 + p2d];
      bool own = (p2d >> 5) == hh;
      int dol = p2d & 31;
      #pragma unroll
      for (int s = 0; s < 8; s++) {
        int t = t0 + s;
        float x3 = xm[(t + 3) * 68 + p2d];
        float a = cb1;
        a = fmaf(cw4.x, x0, a); a = fmaf(cw4.y, x1, a);
        a = fmaf(cw4.z, x2, a); a = fmaf(cw4.w, x3, a);
        float uu = a * sigmoidf_(a);
        ubS[t * 72 + p2d] = f2bf(uu);
        if (own) uT[dol * 68 + t] = uu;
        x0 = x1; x1 = x2; x2 = x3;
      }
    }
    __syncthreads();                        // C: u ready
    // ---- phase3 (MFMA): xdbl = xp_w @ u ; dt -> dt01, B/C -> bcT ----
    {
      {   // job A: (otA, ttA)
        int t = (ttA << 4) + li;
        const char* ub = smem + UBF_OFF + t * 144 + (cig8 << 1);
        bf16x8 b0 = *reinterpret_cast<const bf16x8*>(ub);
        bf16x8 b1 = *reinterpret_cast<const bf16x8*>(ub + 64);
        f32x4 acc = {0.f, 0.f, 0.f, 0.f};
        acc = MFMA16(xpa0, b0, acc);
        acc = MFMA16(xpa1, b1, acc);
        int jb = (otA << 4) + ((lane >> 4) << 2);
        #pragma unroll
        for (int q = 0; q < 4; q++) {
          int j = jb + q;
          if (j < 2) dt01[(t << 1) + j] = acc[q];
          else bcT[(j - 2) * 68 + t] = acc[q];
        }
      }
      if (w < 4) {   // job B: (ot=2, tt=w) -> only j=32,33 live
        int t = (w << 4) + li;
        const char* ub = smem + UBF_OFF + t * 144 + (cig8 << 1);
        bf16x8 b0 = *reinterpret_cast<const bf16x8*>(ub);
        bf16x8 b1 = *reinterpret_cast<const bf16x8*>(ub + 64);
        f32x4 acc = {0.f, 0.f, 0.f, 0.f};
        acc = MFMA16(xpb0, b0, acc);
        acc = MFMA16(xpb1, b1, acc);
        if ((lane >> 4) == 0) {
          bcT[30 * 68 + t] = acc[0];
          bcT[31 * 68 + t] = acc[1];
        }
      }
    }
    __syncthreads();                        // D: bcT, dt01 ready
    // ---- phase4: delta = softplus(dt @ dt_w^T + dt_b) -> dlS (own half, d-major) ----
    {
      int t = tid >> 3;
      float d0 = dt01[t * 2], d1 = dt01[t * 2 + 1];
      #pragma unroll
      for (int q = 0; q < 4; q++) {
        int dg = (hh << 5) + (dd << 2) + q;
        float pre = fmaf(d0, dtwS[2 * dg], fmaf(d1, dtwS[2 * dg + 1], dtbS[dg]));
        float dl_ = (pre > 20.f) ? pre : log1pf(__expf(pre));
        dlS[((dd << 2) + q) * 68 + t] = dl_;
      }
    }
    __syncthreads();                        // E: dlS ready
    // ---- scan: 64 sequential steps, float4 LDS reads ----
    {
      const float* dr = &dlS[sdl * 68];
      const float* ur = &uT[sdl * 68];
      const float* zr = &zsT[sdl * 68];
      const float* Br = &bcT[sn * 68];
      const float* Cr = &bcT[(16 + sn) * 68];
      for (int t = 0; t < 64; t += 4) {
        float4 dv = *reinterpret_cast<const float4*>(&dr[t]);
        float4 uv = *reinterpret_cast<const float4*>(&ur[t]);
        float4 zv = *reinterpret_cast<const float4*>(&zr[t]);
        float4 Bv = *reinterpret_cast<const float4*>(&Br[t]);
        float4 Cv = *reinterpret_cast<const float4*>(&Cr[t]);
        float e0 = __expf(dv.x * Areg), e1 = __expf(dv.y * Areg);
        float e2 = __expf(dv.z * Areg), e3 = __expf(dv.w * Areg);
        float k0 = dv.x * uv.x * Bv.x, k1 = dv.y * uv.y * Bv.y;
        float k2 = dv.z * uv.z * Bv.z, k3 = dv.w * uv.w * Bv.w;
        float c0 = Cv.x * zv.x, c1 = Cv.y * zv.y;
        float c2 = Cv.z * zv.z, c3 = Cv.w * zv.w;
        hst = fmaf(e0, hst, k0); acc_n = fmaf(hst, c0, acc_n);
        hst = fmaf(e1, hst, k1); acc_n = fmaf(hst, c1, acc_n);
        hst = fmaf(e2, hst, k2); acc_n = fmaf(hst, c2, acc_n);
        hst = fmaf(e3, hst, k3); acc_n = fmaf(hst, c3, acc_n);
        acc_u = fmaf(uv.x, zv.x, acc_u); acc_u = fmaf(uv.y, zv.y, acc_u);
        acc_u = fmaf(uv.z, zv.z, acc_u); acc_u = fmaf(uv.w, zv.w, acc_u);
      }
    }
  }
  float y = acc_n;
  y += __shfl_xor(y, 1); y += __shfl_xor(y, 2);
  y += __shfl_xor(y, 4); y += __shfl_xor(y, 8);
  if (sn == 0)
    ybar[(b << 6) + sdg] = (y + Dp[sdg] * acc_u) * (1.f / 1024.f);
}

// ---------------- K3a: conv1 3x3 VALID (32->32) + BN1 + ReLU, MFMA, -> c1_bf -------------
__global__ __launch_bounds__(256) void k_conv1m(
    const unsigned short* __restrict__ p_bf, const unsigned short* __restrict__ Wf1,
    const float* __restrict__ cbias,
    const float* __restrict__ g, const float* __restrict__ be,
    const float* __restrict__ mm, const float* __restrict__ vv,
    unsigned short* __restrict__ c1_bf)
{
  __shared__ __align__(16) unsigned short inS[8 * 32 * 40];  // [row][x][ci pad40]
  int b = blockIdx.x / 5, s = blockIdx.x % 5;
  int y0 = s * 6;
  int tid = threadIdx.x, lane = tid & 63, w = tid >> 6;
  int li = lane & 15, cig8 = (lane >> 4) << 3;
  for (int uu = tid; uu < 1024; uu += 256) {
    int r = uu >> 7, rem = uu & 127;
    uint4 v = *reinterpret_cast<const uint4*>(
        &p_bf[((((size_t)b << 10) + (y0 + r) * 32) << 5) + rem * 8]);
    int xx = rem >> 2, cg = rem & 3;
    *reinterpret_cast<uint4*>(&inS[(r * 32 + xx) * 40 + cg * 8]) = v;
  }
  bf16x8 aw[9][2];
  #pragma unroll
  for (int t = 0; t < 9; t++)
    #pragma unroll
    for (int m = 0; m < 2; m++)
      aw[t][m] = *reinterpret_cast<const bf16x8*>(&Wf1[(((t << 1) + m) * 64 + lane) * 8]);
  float scv[2][4], sbv[2][4];
  #pragma unroll
  for (int m = 0; m < 2; m++)
    #pragma unroll
    for (int j = 0; j < 4; j++) {
      int co = m * 16 + ((lane >> 4) << 2) + j;
      float sc = g[co] * rsqrtf(vv[co] + 1e-5f);
      scv[m][j] = sc;
      sbv[m][j] = fmaf(cbias[co] - mm[co], sc, be[co]);
    }
  __syncthreads();
  #pragma unroll
  for (int q = 0; q < 3; q++) {
    int pf = w + q * 4;
    int p = pf * 16 + li;
    int pv = (p < 180) ? p : 0;
    int ry = pv / 30, rx = pv % 30;
    f32x4 a0 = {0.f, 0.f, 0.f, 0.f}, a1 = {0.f, 0.f, 0.f, 0.f};
    #pragma unroll
    for (int t = 0; t < 9; t++) {
      int dy = t / 3, dx = t % 3;
      bf16x8 bfr = *reinterpret_cast<const bf16x8*>(
          &inS[((ry + dy) * 32 + rx + dx) * 40 + cig8]);
      a0 = MFMA16(aw[t][0], bfr, a0);
      a1 = MFMA16(aw[t][1], bfr, a1);
    }
    if (p < 180) {
      size_t obase = ((size_t)b * 900 + (size_t)(y0 + ry) * 30 + rx) << 5;
      #pragma unroll
      for (int m = 0; m < 2; m++) {
        f32x4 av = m ? a1 : a0;
        ushort4 pk;
        pk.x = f2bf(fmaxf(fmaf(av[0], scv[m][0], sbv[m][0]), 0.f));
        pk.y = f2bf(fmaxf(fmaf(av[1], scv[m][1], sbv[m][1]), 0.f));
        pk.z = f2bf(fmaxf(fmaf(av[2], scv[m][2], sbv[m][2]), 0.f));
        pk.w = f2bf(fmaxf(fmaf(av[3], scv[m][3], sbv[m][3]), 0.f));
        *reinterpret_cast<ushort4*>(&c1_bf[obase + m * 16 + ((lane >> 4) << 2)]) = pk;
      }
    }
  }
}

// ---------------- K3b: conv2 3x3 VALID (32->128) + BN2 + ReLU + spatial-sum, MFMA --------
__global__ __launch_bounds__(256) void k_conv2m(
    const unsigned short* __restrict__ c1_bf, const unsigned short* __restrict__ Wf2,
    const float* __restrict__ cb2,
    const float* __restrict__ g, const float* __restrict__ be,
    const float* __restrict__ mm, const float* __restrict__ vv,
    float* __restrict__ cnn_sum)
{
  __shared__ __align__(16) unsigned short inS[6 * 30 * 40];
  int b = blockIdx.x / 7, s = blockIdx.x % 7;
  int y0 = s * 4;
  int tid = threadIdx.x, lane = tid & 63, w = tid >> 6;
  int li = lane & 15, cig8 = (lane >> 4) << 3;
  for (int uu = tid; uu < 720; uu += 256) {
    int r = uu / 120, rem = uu % 120;
    uint4 v = *reinterpret_cast<const uint4*>(
        &c1_bf[(((size_t)b * 900 + (size_t)(y0 + r) * 30) << 5) + rem * 8]);
    int xx = rem >> 2, cg = rem & 3;
    *reinterpret_cast<uint4*>(&inS[(r * 30 + xx) * 40 + cg * 8]) = v;
  }
  bf16x8 aw[9][2];
  #pragma unroll
  for (int t = 0; t < 9; t++)
    #pragma unroll
    for (int m = 0; m < 2; m++)
      aw[t][m] = *reinterpret_cast<const bf16x8*>(&Wf2[(((t << 3) + (w << 1) + m) * 64 + lane) * 8]);
  float scv[2][4], sbv[2][4];
  float psum[2][4] = {{0.f,0.f,0.f,0.f},{0.f,0.f,0.f,0.f}};
  #pragma unroll
  for (int m = 0; m < 2; m++)
    #pragma unroll
    for (int j = 0; j < 4; j++) {
      int co = (w << 5) + m * 16 + ((lane >> 4) << 2) + j;
      float sc = g[co] * rsqrtf(vv[co] + 1e-5f);
      scv[m][j] = sc;
      sbv[m][j] = fmaf(cb2[co] - mm[co], sc, be[co]);
    }
  __syncthreads();
  #pragma unroll
  for (int pf = 0; pf < 7; pf++) {
    int p = pf * 16 + li;
    int ry = p / 28, rx = p % 28;
    f32x4 a0 = {0.f, 0.f, 0.f, 0.f}, a1 = {0.f, 0.f, 0.f, 0.f};
    #pragma unroll
    for (int t = 0; t < 9; t++) {
      int dy = t / 3, dx = t % 3;
      bf16x8 bfr = *reinterpret_cast<const bf16x8*>(
          &inS[((ry + dy) * 30 + rx + dx) * 40 + cig8]);
      a0 = MFMA16(aw[t][0], bfr, a0);
      a1 = MFMA16(aw[t][1], bfr, a1);
    }
    #pragma unroll
    for (int j = 0; j < 4; j++) {
      psum[0][j] += fmaxf(fmaf(a0[j], scv[0][j], sbv[0][j]), 0.f);
      psum[1][j] += fmaxf(fmaf(a1[j], scv[1][j], sbv[1][j]), 0.f);
    }
  }
  #pragma unroll
  for (int m = 0; m < 2; m++)
    #pragma unroll
    for (int j = 0; j < 4; j++) {
      float v = psum[m][j];
      v += __shfl_xor(v, 1); v += __shfl_xor(v, 2);
      v += __shfl_xor(v, 4); v += __shfl_xor(v, 8);
      if (li == 0) {
        int co = (w << 5) + m * 16 + ((lane >> 4) << 2) + j;
        atomicAdd(&cnn_sum[((size_t)b << 7) + co], v);
      }
    }
}

// ---------------- K4: out = ybar @ W2^T + fc_b + cnn_sum/784 ----------------
__global__ __launch_bounds__(256) void k_final(
    const float* __restrict__ ybar, const float* __restrict__ W2,
    const float* __restrict__ fc_b, const float* __restrict__ cnn_sum,
    float* __restrict__ out)
{
  int i = blockIdx.x * 256 + threadIdx.x;   // 16384
  int b = i >> 7, f = i & 127;
  float a = 0.f;
  #pragma unroll
  for (int d2 = 0; d2 < 64; d2++) a = fmaf(ybar[(b << 6) + d2], W2[(f << 6) + d2], a);
  out[i] = a + fc_b[f] + cnn_sum[i] * (1.f / 784.f);
}

extern "C" void kernel_launch(void* const* d_in, const int* in_sizes, int n_in,
                              void* d_out, int out_size, void* d_ws, size_t ws_size,
                              hipStream_t stream) {
  (void)in_sizes; (void)n_in; (void)out_size; (void)ws_size;
  const float* x         = (const float*)d_in[0];
  const float* proj_w    = (const float*)d_in[1];
  const float* proj_b    = (const float*)d_in[2];
  const float* bn0_g     = (const float*)d_in[3];
  const float* bn0_b     = (const float*)d_in[4];
  const float* bn0_m     = (const float*)d_in[5];
  const float* bn0_v     = (const float*)d_in[6];
  const float* in_proj_w = (const float*)d_in[7];
  const float* conv_w    = (const float*)d_in[8];
  const float* conv_b    = (const float*)d_in[9];
  const float* x_proj_w  = (const float*)d_in[10];
  const float* dt_w      = (const float*)d_in[11];
  const float* dt_b      = (const float*)d_in[12];
  const float* A_log     = (const float*)d_in[13];
  const float* Dp        = (const float*)d_in[14];
  const float* out_proj_w= (const float*)d_in[15];
  const float* fc_w      = (const float*)d_in[16];
  const float* fc_b      = (const float*)d_in[17];
  const float* c1_w      = (const float*)d_in[18];
  const float* c1_b      = (const float*)d_in[19];
  const float* bn1_g     = (const float*)d_in[20];
  const float* bn1_b     = (const float*)d_in[21];
  const float* bn1_m     = (const float*)d_in[22];
  const float* bn1_v     = (const float*)d_in[23];
  const float* c2_w      = (const float*)d_in[24];
  const float* c2_b      = (const float*)d_in[25];
  const float* bn2_g     = (const float*)d_in[26];
  const float* bn2_b     = (const float*)d_in[27];
  const float* bn2_m     = (const float*)d_in[28];
  const float* bn2_v     = (const float*)d_in[29];
  float* out = (float*)d_out;
  float* ws  = (float*)d_ws;
  // workspace layout (float slots); ~16 MB
  float* ybar    = ws;                                        // 8192
  float* cnn_sum = ws + 8192;                                 // 16384
  float* W2      = ws + 24576;                                // 8192
  unsigned short* p_bf  = (unsigned short*)(ws + 32768);      // 4194304 bf16
  unsigned short* c1_bf = (unsigned short*)(ws + 2129920);    // 3686400 bf16
  unsigned short* Wf1   = (unsigned short*)(ws + 3973120);    // 9216 bf16
  unsigned short* Wf2   = (unsigned short*)(ws + 3977728);    // 36864 bf16
  unsigned short* Wfin  = (unsigned short*)(ws + 3996160);    // 4096 bf16
  unsigned short* Wfxp  = (unsigned short*)(ws + 3998208);    // 3072 bf16

  k_prep<<<dim3(304), dim3(256), 0, stream>>>(c1_w, c2_w, fc_w, out_proj_w, in_proj_w, x_proj_w,
                                              Wf1, Wf2, Wfin, Wfxp, W2, cnn_sum);
  k_proj_bn<<<dim3(512), dim3(256), 0, stream>>>(x, proj_w, proj_b, bn0_g, bn0_b, bn0_m, bn0_v, p_bf);
  k_mamba<<<dim3(256), dim3(512), 0, stream>>>(p_bf, Wfin, Wfxp, conv_w, conv_b, dt_w, dt_b,
                                               A_log, Dp, ybar);
  k_conv1m<<<dim3(640), dim3(256), 0, stream>>>(p_bf, Wf1, c1_b, bn1_g, bn1_b, bn1_m, bn1_v, c1_bf);
  k_conv2m<<<dim3(896), dim3(256), 0, stream>>>(c1_bf, Wf2, c2_b, bn2_g, bn2_b, bn2_m, bn2_v, cnn_sum);
  k_final<<<dim3(64), dim3(256), 0, stream>>>(ybar, W2, fc_b, cnn_sum, out);
}

// Round 7
// 177.102 us; speedup vs baseline: 3.0874x; 1.1072x over previous
//
#include <hip/hip_runtime.h>
#include <cstdint>

typedef short bf16x8 __attribute__((ext_vector_type(8)));
typedef float f32x4 __attribute__((ext_vector_type(4)));
#define MFMA16(a, b, c) __builtin_amdgcn_mfma_f32_16x16x32_bf16((a), (b), (c), 0, 0, 0)

static __device__ __forceinline__ float sigmoidf_(float x) { return 1.f / (1.f + __expf(-x)); }
static __device__ __forceinline__ unsigned short f2bf(float f) {
  union { float f; unsigned u; } v; v.f = f;
  unsigned r = v.u + 0x7FFF + ((v.u >> 16) & 1);
  return (unsigned short)(r >> 16);
}
static __device__ __forceinline__ void bf2x(unsigned p, float& lo, float& hi) {
  union { unsigned u; float f; } a, bb;
  a.u = p << 16; bb.u = p & 0xffff0000u;
  lo = a.f; hi = bb.f;
}

// ---------------- K0: weight prep (frag layouts), W2, zero cnn_sum ----------------------
__global__ __launch_bounds__(256) void k_prep(
    const float* __restrict__ c1_w, const float* __restrict__ c2_w,
    const float* __restrict__ fc_w, const float* __restrict__ opw,
    const float* __restrict__ in_w, const float* __restrict__ xp_w,
    unsigned short* __restrict__ Wf1, unsigned short* __restrict__ Wf2,
    unsigned short* __restrict__ Wfin, unsigned short* __restrict__ Wfxp,
    float* __restrict__ W2, float* __restrict__ cnn_sum)
{
  int i = blockIdx.x * 256 + threadIdx.x;
  if (i < 36864) {           // Wf2[t][cf 0..7][lane][j] = c2_w[co][ci][dy][dx]
    int j = i & 7, l = (i >> 3) & 63, m = (i >> 9) & 7, t = i >> 12;
    int co = m * 16 + (l & 15), ci = ((l >> 4) << 3) + j;
    Wf2[i] = f2bf(c2_w[(size_t)(co * 32 + ci) * 9 + t]);
  } else if (i < 46080) {    // Wf1[t][cf 0..1][lane][j]
    int ii = i - 36864;
    int j = ii & 7, l = (ii >> 3) & 63, m = (ii >> 9) & 1, t = ii >> 10;
    int co = m * 16 + (l & 15), ci = ((l >> 4) << 3) + j;
    Wf1[ii] = f2bf(c1_w[(size_t)(co * 32 + ci) * 9 + t]);
  } else if (i < 54272) {    // W2 = fc_w @ out_proj_w (128x64)
    int ii = i - 46080;
    int f = ii >> 6, d2 = ii & 63;
    float a = 0.f;
    #pragma unroll
    for (int dm = 0; dm < 32; dm++) a = fmaf(fc_w[(f << 5) + dm], opw[(dm << 6) + d2], a);
    W2[ii] = a;
  } else if (i < 70656) {
    cnn_sum[i - 54272] = 0.f;
  } else if (i < 74752) {    // Wfin[ot 0..7][lane][j] = in_w[o][c]
    int ii = i - 70656;
    int j = ii & 7, l = (ii >> 3) & 63, ot = ii >> 9;
    int o = (ot << 4) + (l & 15), c = ((l >> 4) << 3) + j;
    Wfin[ii] = f2bf(in_w[(o << 5) + c]);
  } else if (i < 77824) {    // Wfxp[ot 0..2][kh 0..1][lane][j] = xp_w[jr][c] (jr>=34 -> 0)
    int ii = i - 74752;
    int j = ii & 7, l = (ii >> 3) & 63, kh = (ii >> 9) & 1, ot = ii >> 10;
    int jr = (ot << 4) + (l & 15), c = (kh << 5) + ((l >> 4) << 3) + j;
    Wfxp[ii] = (jr < 34) ? f2bf(xp_w[(jr << 6) + c]) : (unsigned short)0;
  }
}

// ---------------- K1: 1x1 conv (proj) + BN0 + ReLU -> p_bf (bf16 tokens) ----------------
__global__ __launch_bounds__(256) void k_proj_bn(
    const float* __restrict__ x, const float* __restrict__ w,
    const float* __restrict__ pb,
    const float* __restrict__ g, const float* __restrict__ be,
    const float* __restrict__ mm, const float* __restrict__ vv,
    unsigned short* __restrict__ p_bf)
{
  __shared__ float wl[6400];        // [c][d] transposed proj_w
  __shared__ float sc[32], sb[32];
  int b = blockIdx.x >> 2, ch = blockIdx.x & 3;
  for (int i = threadIdx.x; i < 6400; i += 256) {
    int c = i >> 5, d = i & 31;
    wl[i] = w[d * 200 + c];
  }
  if (threadIdx.x < 32) {
    int d = threadIdx.x;
    float s = g[d] * rsqrtf(vv[d] + 1e-5f);
    sc[d] = s;
    sb[d] = fmaf(pb[d] - mm[d], s, be[d]);
  }
  __syncthreads();
  int l = (ch << 8) + threadIdx.x;
  const float* xp = x + (size_t)b * 200 * 1024 + l;
  float acc[32];
  #pragma unroll
  for (int d = 0; d < 32; d++) acc[d] = 0.f;
  for (int c = 0; c < 200; c++) {
    float xv = xp[(size_t)c << 10];
    const float* wr = &wl[c << 5];
    #pragma unroll
    for (int d = 0; d < 32; d++) acc[d] = fmaf(xv, wr[d], acc[d]);
  }
  #pragma unroll
  for (int d = 0; d < 32; d++) {
    float val = fmaf(acc[d], sc[d], sb[d]);
    acc[d] = fmaxf(val, 0.f);
  }
  unsigned short* pbf = p_bf + (((size_t)b << 10) + l) * 32;
  #pragma unroll
  for (int k = 0; k < 4; k++) {
    uint4 q;
    q.x = (unsigned)f2bf(acc[8*k+0]) | ((unsigned)f2bf(acc[8*k+1]) << 16);
    q.y = (unsigned)f2bf(acc[8*k+2]) | ((unsigned)f2bf(acc[8*k+3]) << 16);
    q.z = (unsigned)f2bf(acc[8*k+4]) | ((unsigned)f2bf(acc[8*k+5]) << 16);
    q.w = (unsigned)f2bf(acc[8*k+6]) | ((unsigned)f2bf(acc[8*k+7]) << 16);
    *reinterpret_cast<uint4*>(pbf + k * 8) = q;
  }
}

// ---------------- K2: chunk-parallel mamba block: phases + intra-chunk scan -> (P,q,R,S) -
// grid 2048 = (b, chunk); 1024 threads (16 waves); 4 barriers; 2 blocks/CU resident.
__global__ __launch_bounds__(1024, 4) void k_mamba(
    const unsigned short* __restrict__ p_bf,
    const unsigned short* __restrict__ Wfin,
    const unsigned short* __restrict__ Wfxp,
    const float* __restrict__ conv_w,    // (64,4)
    const float* __restrict__ conv_b,    // (64)
    const float* __restrict__ dt_w,      // (64,2)
    const float* __restrict__ dt_b,      // (64)
    const float* __restrict__ A_log,     // (64,16)
    float* __restrict__ pqrs,            // (128,16,64,16,4)
    float* __restrict__ au_g)            // (128,16,64)
{
  __shared__ __align__(16) char smem[57136];
  float* xm  = (float*)smem;                               // [67][68] f32 (xz rows; r = t+3)
  float* dlS = (float*)smem;                               // [64][68] alias (phase4+)
  unsigned short* ubS = (unsigned short*)(smem + 18224);   // [64][72] bf16 u, t-major
  unsigned short* uTb = (unsigned short*)(smem + 27440);   // [64][72] bf16 u, d-major
  unsigned short* zTb = (unsigned short*)(smem + 36656);   // [64][72] bf16 silu(z), d-major
  float* bcT  = (float*)(smem + 45872);                    // [32][68] B rows 0..15, C 16..31
  float* dt01 = (float*)(smem + 54576);                    // [64][2]
  float* cwS  = (float*)(smem + 55088);                    // [64][4]
  float* cbS  = (float*)(smem + 56112);                    // [64]
  float* dtwS = (float*)(smem + 56368);                    // [64][2]
  float* dtbS = (float*)(smem + 56880);                    // [64]

  int b = blockIdx.x >> 4, ch = blockIdx.x & 15;
  int tid = threadIdx.x, lane = tid & 63, w = tid >> 6;
  int li = lane & 15, cig8 = (lane >> 4) << 3;

  // stage small weights (no barrier needed: first consumer is after barrier B)
  if (tid < 256) cwS[tid] = conv_w[tid];
  else if (tid < 320) cbS[tid - 256] = conv_b[tid - 256];
  else if (tid < 448) dtwS[tid - 320] = dt_w[tid - 320];
  else if (tid < 512) dtbS[tid - 448] = dt_b[tid - 448];

  const unsigned short* pbf_b = p_bf + ((size_t)b << 15);

  // ---- phase1 (MFMA): xz = in_w @ tok ; x (rows -3..63) -> xm ; silu(z) -> zTb ----
  // jobs 0..19: x (ot=j/5, row-tile tt=j%5, rows r=tt*16+li, xz token = ch*64+r-3)
  // jobs 20..35: z (zot, t-tile)
  for (int j = w; j < 36; j += 16) {
    if (j < 20) {
      int ot = j / 5, tt = j % 5;
      int r = tt * 16 + li;
      int tg = (ch << 6) + r - 3;
      bf16x8 bfr = {0,0,0,0,0,0,0,0};
      if (r < 67 && tg >= 0)
        bfr = *reinterpret_cast<const bf16x8*>(pbf_b + ((size_t)tg << 5) + cig8);
      bf16x8 aW = *reinterpret_cast<const bf16x8*>(&Wfin[((ot << 6) + lane) << 3]);
      f32x4 acc = {0.f, 0.f, 0.f, 0.f};
      acc = MFMA16(aW, bfr, acc);
      if (r < 67)
        *reinterpret_cast<float4*>(&xm[r * 68 + (ot << 4) + ((lane >> 4) << 2)]) =
            make_float4(acc[0], acc[1], acc[2], acc[3]);
    } else {
      int jz = j - 20;
      int zot = jz >> 2, tt = jz & 3;
      int t = tt * 16 + li;
      int tg = (ch << 6) + t;
      bf16x8 bfr = *reinterpret_cast<const bf16x8*>(pbf_b + ((size_t)tg << 5) + cig8);
      bf16x8 aW = *reinterpret_cast<const bf16x8*>(&Wfin[(((4 + zot) << 6) + lane) << 3]);
      f32x4 acc = {0.f, 0.f, 0.f, 0.f};
      acc = MFMA16(aW, bfr, acc);
      int dzb = (zot << 4) + ((lane >> 4) << 2);
      #pragma unroll
      for (int q = 0; q < 4; q++) {
        float zz = acc[q];
        zTb[(dzb + q) * 72 + t] = f2bf(zz * sigmoidf_(zz));
      }
    }
  }
  __syncthreads();                        // B: xm, zTb, weights ready
  // ---- phase2: causal dwconv(4) + silu -> ubS (t-major), uTb (d-major) ----
  {
    int d2 = tid & 63, oct = tid >> 6;
    int t0 = oct << 2;
    float4 cw4 = *reinterpret_cast<const float4*>(&cwS[d2 << 2]);
    float cb1 = cbS[d2];
    float x0 = xm[t0 * 68 + d2], x1 = xm[(t0 + 1) * 68 + d2], x2 = xm[(t0 + 2) * 68 + d2];
    unsigned short up[4];
    #pragma unroll
    for (int s = 0; s < 4; s++) {
      int t = t0 + s;
      float x3 = xm[(t + 3) * 68 + d2];
      float a = cb1;
      a = fmaf(cw4.x, x0, a); a = fmaf(cw4.y, x1, a);
      a = fmaf(cw4.z, x2, a); a = fmaf(cw4.w, x3, a);
      float uu = a * sigmoidf_(a);
      unsigned short ub_ = f2bf(uu);
      ubS[t * 72 + d2] = ub_;
      up[s] = ub_;
      x0 = x1; x1 = x2; x2 = x3;
    }
    uint2 pk;
    pk.x = (unsigned)up[0] | ((unsigned)up[1] << 16);
    pk.y = (unsigned)up[2] | ((unsigned)up[3] << 16);
    *reinterpret_cast<uint2*>(&uTb[d2 * 72 + t0]) = pk;
  }
  __syncthreads();                        // C: u ready
  // ---- phase3 (MFMA): xdbl = xp_w @ u ; dt -> dt01, B/C -> bcT ----
  if (w < 12) {
    int ot = w >> 2, tt = w & 3;
    int t = tt * 16 + li;
    const unsigned short* ub = &ubS[t * 72];
    bf16x8 b0 = *reinterpret_cast<const bf16x8*>(ub + cig8);
    bf16x8 b1 = *reinterpret_cast<const bf16x8*>(ub + 32 + cig8);
    bf16x8 a0 = *reinterpret_cast<const bf16x8*>(&Wfxp[(((ot << 1) + 0) * 64 + lane) << 3]);
    bf16x8 a1 = *reinterpret_cast<const bf16x8*>(&Wfxp[(((ot << 1) + 1) * 64 + lane) << 3]);
    f32x4 acc = {0.f, 0.f, 0.f, 0.f};
    acc = MFMA16(a0, b0, acc);
    acc = MFMA16(a1, b1, acc);
    int jb = (ot << 4) + ((lane >> 4) << 2);
    #pragma unroll
    for (int q = 0; q < 4; q++) {
      int jj = jb + q;
      if (jj < 2) dt01[(t << 1) + jj] = acc[q];
      else if (jj < 34) bcT[(jj - 2) * 68 + t] = acc[q];
    }
  }
  __syncthreads();                        // D: bcT, dt01 ready
  // ---- phase4: delta = softplus(dt @ dt_w^T + dt_b) -> dlS (aliases xm; xm dead) ----
  {
    int t = tid >> 4, dq = (tid & 15) << 2;
    float d0 = dt01[t << 1], d1 = dt01[(t << 1) + 1];
    #pragma unroll
    for (int q = 0; q < 4; q++) {
      int dg = dq + q;
      float pre = fmaf(d0, dtwS[dg << 1], fmaf(d1, dtwS[(dg << 1) + 1], dtbS[dg]));
      float dl_ = (pre > 20.f) ? pre : log1pf(__expf(pre));
      dlS[dg * 68 + t] = dl_;
    }
  }
  __syncthreads();                        // E: dlS ready
  // ---- intra-chunk scan: h_out = P h_in + q ; y = R h_in + S ; au = sum u*z ----
  {
    int sd = tid >> 4, sn = tid & 15;
    float A = -__expf(A_log[(sd << 4) + sn]);
    float P = 1.f, qq = 0.f, R = 0.f, S = 0.f, au = 0.f;
    const float* dr = &dlS[sd * 68];
    const unsigned short* ur = &uTb[sd * 72];
    const unsigned short* zr = &zTb[sd * 72];
    const float* Br = &bcT[sn * 68];
    const float* Cr = &bcT[(16 + sn) * 68];
    for (int t = 0; t < 64; t += 4) {
      float4 dv = *reinterpret_cast<const float4*>(dr + t);
      uint2 uu = *reinterpret_cast<const uint2*>(ur + t);
      uint2 zz = *reinterpret_cast<const uint2*>(zr + t);
      float4 Bv = *reinterpret_cast<const float4*>(Br + t);
      float4 Cv = *reinterpret_cast<const float4*>(Cr + t);
      float u0, u1, u2, u3, z0, z1, z2, z3;
      bf2x(uu.x, u0, u1); bf2x(uu.y, u2, u3);
      bf2x(zz.x, z0, z1); bf2x(zz.y, z2, z3);
      float e, k, cz;
      e = __expf(dv.x * A); k = dv.x * u0 * Bv.x; P = e * P; qq = fmaf(e, qq, k);
      cz = Cv.x * z0; R = fmaf(cz, P, R); S = fmaf(cz, qq, S); au = fmaf(u0, z0, au);
      e = __expf(dv.y * A); k = dv.y * u1 * Bv.y; P = e * P; qq = fmaf(e, qq, k);
      cz = Cv.y * z1; R = fmaf(cz, P, R); S = fmaf(cz, qq, S); au = fmaf(u1, z1, au);
      e = __expf(dv.z * A); k = dv.z * u2 * Bv.z; P = e * P; qq = fmaf(e, qq, k);
      cz = Cv.z * z2; R = fmaf(cz, P, R); S = fmaf(cz, qq, S); au = fmaf(u2, z2, au);
      e = __expf(dv.w * A); k = dv.w * u3 * Bv.w; P = e * P; qq = fmaf(e, qq, k);
      cz = Cv.w * z3; R = fmaf(cz, P, R); S = fmaf(cz, qq, S); au = fmaf(u3, z3, au);
    }
    size_t idx = ((((size_t)b << 4) + ch) << 10) + (sd << 4) + sn;
    *reinterpret_cast<float4*>(pqrs + (idx << 2)) = make_float4(P, qq, R, S);
    if (sn == 0) au_g[((((size_t)b << 4) + ch) << 6) + sd] = au;
  }
}

// ---------------- K2b: cross-chunk combine -> ybar ----------------
__global__ __launch_bounds__(512) void k_comb(
    const float* __restrict__ pqrs, const float* __restrict__ au_g,
    const float* __restrict__ Dp, float* __restrict__ ybar)
{
  int b = blockIdx.x >> 1, hh = blockIdx.x & 1;
  int tid = threadIdx.x;
  int sd = (hh << 5) + (tid >> 4), sn = tid & 15;
  float4 pq[16];
  #pragma unroll
  for (int c = 0; c < 16; c++) {
    size_t idx = ((((size_t)b << 4) + c) << 10) + (sd << 4) + sn;
    pq[c] = *reinterpret_cast<const float4*>(pqrs + (idx << 2));
  }
  float h = 0.f, y = 0.f;
  #pragma unroll
  for (int c = 0; c < 16; c++) {
    y = fmaf(pq[c].z, h, y + pq[c].w);
    h = fmaf(pq[c].x, h, pq[c].y);
  }
  float val = y + Dp[sd] * au_g[((((size_t)b << 4) + sn) << 6) + sd];
  val += __shfl_xor(val, 1); val += __shfl_xor(val, 2);
  val += __shfl_xor(val, 4); val += __shfl_xor(val, 8);
  if (sn == 0) ybar[(b << 6) + sd] = val * (1.f / 1024.f);
}

// ---------------- K3a: conv1 3x3 VALID (32->32) + BN1 + ReLU, MFMA, -> c1_bf -------------
__global__ __launch_bounds__(256) void k_conv1m(
    const unsigned short* __restrict__ p_bf, const unsigned short* __restrict__ Wf1,
    const float* __restrict__ cbias,
    const float* __restrict__ g, const float* __restrict__ be,
    const float* __restrict__ mm, const float* __restrict__ vv,
    unsigned short* __restrict__ c1_bf)
{
  __shared__ __align__(16) unsigned short inS[8 * 32 * 40];  // [row][x][ci pad40]
  int b = blockIdx.x / 5, s = blockIdx.x % 5;
  int y0 = s * 6;
  int tid = threadIdx.x, lane = tid & 63, w = tid >> 6;
  int li = lane & 15, cig8 = (lane >> 4) << 3;
  for (int uu = tid; uu < 1024; uu += 256) {
    int r = uu >> 7, rem = uu & 127;
    uint4 v = *reinterpret_cast<const uint4*>(
        &p_bf[((((size_t)b << 10) + (y0 + r) * 32) << 5) + rem * 8]);
    int xx = rem >> 2, cg = rem & 3;
    *reinterpret_cast<uint4*>(&inS[(r * 32 + xx) * 40 + cg * 8]) = v;
  }
  bf16x8 aw[9][2];
  #pragma unroll
  for (int t = 0; t < 9; t++)
    #pragma unroll
    for (int m = 0; m < 2; m++)
      aw[t][m] = *reinterpret_cast<const bf16x8*>(&Wf1[(((t << 1) + m) * 64 + lane) * 8]);
  float scv[2][4], sbv[2][4];
  #pragma unroll
  for (int m = 0; m < 2; m++)
    #pragma unroll
    for (int j = 0; j < 4; j++) {
      int co = m * 16 + ((lane >> 4) << 2) + j;
      float sc = g[co] * rsqrtf(vv[co] + 1e-5f);
      scv[m][j] = sc;
      sbv[m][j] = fmaf(cbias[co] - mm[co], sc, be[co]);
    }
  __syncthreads();
  #pragma unroll
  for (int q = 0; q < 3; q++) {
    int pf = w + q * 4;
    int p = pf * 16 + li;
    int pv = (p < 180) ? p : 0;
    int ry = pv / 30, rx = pv % 30;
    f32x4 a0 = {0.f, 0.f, 0.f, 0.f}, a1 = {0.f, 0.f, 0.f, 0.f};
    #pragma unroll
    for (int t = 0; t < 9; t++) {
      int dy = t / 3, dx = t % 3;
      bf16x8 bfr = *reinterpret_cast<const bf16x8*>(
          &inS[((ry + dy) * 32 + rx + dx) * 40 + cig8]);
      a0 = MFMA16(aw[t][0], bfr, a0);
      a1 = MFMA16(aw[t][1], bfr, a1);
    }
    if (p < 180) {
      size_t obase = ((size_t)b * 900 + (size_t)(y0 + ry) * 30 + rx) << 5;
      #pragma unroll
      for (int m = 0; m < 2; m++) {
        f32x4 av = m ? a1 : a0;
        ushort4 pk;
        pk.x = f2bf(fmaxf(fmaf(av[0], scv[m][0], sbv[m][0]), 0.f));
        pk.y = f2bf(fmaxf(fmaf(av[1], scv[m][1], sbv[m][1]), 0.f));
        pk.z = f2bf(fmaxf(fmaf(av[2], scv[m][2], sbv[m][2]), 0.f));
        pk.w = f2bf(fmaxf(fmaf(av[3], scv[m][3], sbv[m][3]), 0.f));
        *reinterpret_cast<ushort4*>(&c1_bf[obase + m * 16 + ((lane >> 4) << 2)]) = pk;
      }
    }
  }
}

// ---------------- K3b: conv2 3x3 VALID (32->128) + BN2 + ReLU + spatial-sum, MFMA --------
__global__ __launch_bounds__(256) void k_conv2m(
    const unsigned short* __restrict__ c1_bf, const unsigned short* __restrict__ Wf2,
    const float* __restrict__ cb2,
    const float* __restrict__ g, const float* __restrict__ be,
    const float* __restrict__ mm, const float* __restrict__ vv,
    float* __restrict__ cnn_sum)
{
  __shared__ __align__(16) unsigned short inS[6 * 30 * 40];
  int b = blockIdx.x / 7, s = blockIdx.x % 7;
  int y0 = s * 4;
  int tid = threadIdx.x, lane = tid & 63, w = tid >> 6;
  int li = lane & 15, cig8 = (lane >> 4) << 3;
  for (int uu = tid; uu < 720; uu += 256) {
    int r = uu / 120, rem = uu % 120;
    uint4 v = *reinterpret_cast<const uint4*>(
        &c1_bf[(((size_t)b * 900 + (size_t)(y0 + r) * 30) << 5) + rem * 8]);
    int xx = rem >> 2, cg = rem & 3;
    *reinterpret_cast<uint4*>(&inS[(r * 30 + xx) * 40 + cg * 8]) = v;
  }
  bf16x8 aw[9][2];
  #pragma unroll
  for (int t = 0; t < 9; t++)
    #pragma unroll
    for (int m = 0; m < 2; m++)
      aw[t][m] = *reinterpret_cast<const bf16x8*>(&Wf2[(((t << 3) + (w << 1) + m) * 64 + lane) * 8]);
  float scv[2][4], sbv[2][4];
  float psum[2][4] = {{0.f,0.f,0.f,0.f},{0.f,0.f,0.f,0.f}};
  #pragma unroll
  for (int m = 0; m < 2; m++)
    #pragma unroll
    for (int j = 0; j < 4; j++) {
      int co = (w << 5) + m * 16 + ((lane >> 4) << 2) + j;
      float sc = g[co] * rsqrtf(vv[co] + 1e-5f);
      scv[m][j] = sc;
      sbv[m][j] = fmaf(cb2[co] - mm[co], sc, be[co]);
    }
  __syncthreads();
  #pragma unroll
  for (int pf = 0; pf < 7; pf++) {
    int p = pf * 16 + li;
    int ry = p / 28, rx = p % 28;
    f32x4 a0 = {0.f, 0.f, 0.f, 0.f}, a1 = {0.f, 0.f, 0.f, 0.f};
    #pragma unroll
    for (int t = 0; t < 9; t++) {
      int dy = t / 3, dx = t % 3;
      bf16x8 bfr = *reinterpret_cast<const bf16x8*>(
          &inS[((ry + dy) * 30 + rx + dx) * 40 + cig8]);
      a0 = MFMA16(aw[t][0], bfr, a0);
      a1 = MFMA16(aw[t][1], bfr, a1);
    }
    #pragma unroll
    for (int j = 0; j < 4; j++) {
      psum[0][j] += fmaxf(fmaf(a0[j], scv[0][j], sbv[0][j]), 0.f);
      psum[1][j] += fmaxf(fmaf(a1[j], scv[1][j], sbv[1][j]), 0.f);
    }
  }
  #pragma unroll
  for (int m = 0; m < 2; m++)
    #pragma unroll
    for (int j = 0; j < 4; j++) {
      float v = psum[m][j];
      v += __shfl_xor(v, 1); v += __shfl_xor(v, 2);
      v += __shfl_xor(v, 4); v += __shfl_xor(v, 8);
      if (li == 0) {
        int co = (w << 5) + m * 16 + ((lane >> 4) << 2) + j;
        atomicAdd(&cnn_sum[((size_t)b << 7) + co], v);
      }
    }
}

// ---------------- K4: out = ybar @ W2^T + fc_b + cnn_sum/784 ----------------
__global__ __launch_bounds__(256) void k_final(
    const float* __restrict__ ybar, const float* __restrict__ W2,
    const float* __restrict__ fc_b, const float* __restrict__ cnn_sum,
    float* __restrict__ out)
{
  int i = blockIdx.x * 256 + threadIdx.x;   // 16384
  int b = i >> 7, f = i & 127;
  float a = 0.f;
  #pragma unroll
  for (int d2 = 0; d2 < 64; d2++) a = fmaf(ybar[(b << 6) + d2], W2[(f << 6) + d2], a);
  out[i] = a + fc_b[f] + cnn_sum[i] * (1.f / 784.f);
}

extern "C" void kernel_launch(void* const* d_in, const int* in_sizes, int n_in,
                              void* d_out, int out_size, void* d_ws, size_t ws_size,
                              hipStream_t stream) {
  (void)in_sizes; (void)n_in; (void)out_size; (void)ws_size;
  const float* x         = (const float*)d_in[0];
  const float* proj_w    = (const float*)d_in[1];
  const float* proj_b    = (const float*)d_in[2];
  const float* bn0_g     = (const float*)d_in[3];
  const float* bn0_b     = (const float*)d_in[4];
  const float* bn0_m     = (const float*)d_in[5];
  const float* bn0_v     = (const float*)d_in[6];
  const float* in_proj_w = (const float*)d_in[7];
  const float* conv_w    = (const float*)d_in[8];
  const float* conv_b    = (const float*)d_in[9];
  const float* x_proj_w  = (const float*)d_in[10];
  const float* dt_w      = (const float*)d_in[11];
  const float* dt_b      = (const float*)d_in[12];
  const float* A_log     = (const float*)d_in[13];
  const float* Dp        = (const float*)d_in[14];
  const float* out_proj_w= (const float*)d_in[15];
  const float* fc_w      = (const float*)d_in[16];
  const float* fc_b      = (const float*)d_in[17];
  const float* c1_w      = (const float*)d_in[18];
  const float* c1_b      = (const float*)d_in[19];
  const float* bn1_g     = (const float*)d_in[20];
  const float* bn1_b     = (const float*)d_in[21];
  const float* bn1_m     = (const float*)d_in[22];
  const float* bn1_v     = (const float*)d_in[23];
  const float* c2_w      = (const float*)d_in[24];
  const float* c2_b      = (const float*)d_in[25];
  const float* bn2_g     = (const float*)d_in[26];
  const float* bn2_b     = (const float*)d_in[27];
  const float* bn2_m     = (const float*)d_in[28];
  const float* bn2_v     = (const float*)d_in[29];
  float* out = (float*)d_out;
  float* ws  = (float*)d_ws;
  // workspace layout (float slots); ~50 MB
  float* ybar    = ws;                                        // 8192
  float* cnn_sum = ws + 8192;                                 // 16384
  float* W2      = ws + 24576;                                // 8192
  float* pqrs    = ws + 32768;                                // 8388608
  float* au_g    = ws + 8421376;                              // 131072
  unsigned short* p_bf  = (unsigned short*)(ws + 8552448);    // 4194304 bf16
  unsigned short* c1_bf = (unsigned short*)(ws + 10649600);   // 3686400 bf16
  unsigned short* Wf1   = (unsigned short*)(ws + 12492800);   // 9216 bf16
  unsigned short* Wf2   = (unsigned short*)(ws + 12497408);   // 36864 bf16
  unsigned short* Wfin  = (unsigned short*)(ws + 12515840);   // 4096 bf16
  unsigned short* Wfxp  = (unsigned short*)(ws + 12517888);   // 3072 bf16

  k_prep<<<dim3(304), dim3(256), 0, stream>>>(c1_w, c2_w, fc_w, out_proj_w, in_proj_w, x_proj_w,
                                              Wf1, Wf2, Wfin, Wfxp, W2, cnn_sum);
  k_proj_bn<<<dim3(512), dim3(256), 0, stream>>>(x, proj_w, proj_b, bn0_g, bn0_b, bn0_m, bn0_v, p_bf);
  k_mamba<<<dim3(2048), dim3(1024), 0, stream>>>(p_bf, Wfin, Wfxp, conv_w, conv_b, dt_w, dt_b,
                                                 A_log, pqrs, au_g);
  k_comb<<<dim3(256), dim3(512), 0, stream>>>(pqrs, au_g, Dp, ybar);
  k_conv1m<<<dim3(640), dim3(256), 0, stream>>>(p_bf, Wf1, c1_b, bn1_g, bn1_b, bn1_m, bn1_v, c1_bf);
  k_conv2m<<<dim3(896), dim3(256), 0, stream>>>(c1_bf, Wf2, c2_b, bn2_g, bn2_b, bn2_m, bn2_v, cnn_sum);
  k_final<<<dim3(64), dim3(256), 0, stream>>>(ybar, W2, fc_b, cnn_sum, out);
}